// Round 1
// baseline (777.969 us; speedup 1.0000x reference)
//
#include <hip/hip_runtime.h>

#define NPTS 16384

struct MidW { const float* W[7]; const float* b[7]; };

// In-place tanh jet: u[13] holds pre-activation jet, becomes activation jet.
// Order: 0:val 1:dx 2:dy 3:dt 4:dxx 5:dxy 6:dyy 7:dxt 8:dyt 9:dxxx 10:dxxy 11:dxyy 12:dyyy
__device__ __forceinline__ void tanh_jet(float u[13]) {
    float s    = tanhf(u[0]);
    float sp   = 1.f - s * s;        // s'
    float spp  = -2.f * s * sp;      // s''
    float sppp = -2.f * (sp * sp + s * spp);  // s'''
    float u1 = u[1], u2 = u[2], u3 = u[3];
    float u4 = u[4], u5 = u[5], u6 = u[6];
    u[0] = s;
    u[1] = sp * u1;
    u[2] = sp * u2;
    u[3] = sp * u3;
    // third order first (uses original u4..u6)
    u[9]  = sppp * u1 * u1 * u1 + 3.f * spp * u1 * u4 + sp * u[9];
    u[10] = sppp * u1 * u1 * u2 + spp * (u4 * u2 + 2.f * u5 * u1) + sp * u[10];
    u[11] = sppp * u1 * u2 * u2 + spp * (u6 * u1 + 2.f * u5 * u2) + sp * u[11];
    u[12] = sppp * u2 * u2 * u2 + 3.f * spp * u2 * u6 + sp * u[12];
    // second order
    u[4] = spp * u1 * u1 + sp * u4;
    u[5] = spp * u1 * u2 + sp * u5;
    u[6] = spp * u2 * u2 + sp * u6;
    u[7] = spp * u1 * u3 + sp * u[7];
    u[8] = spp * u2 * u3 + sp * u[8];
}

__global__ __launch_bounds__(256, 2)
void pinn_jet_kernel(const float* __restrict__ W0, const float* __restrict__ b0,
                     MidW mw,
                     const float* __restrict__ W8, const float* __restrict__ b8,
                     const float* __restrict__ xs, const float* __restrict__ ys,
                     const float* __restrict__ ts_, const float* __restrict__ l1p,
                     const float* __restrict__ l2p, float* __restrict__ out)
{
    // Wt: transposed half-layer weights, pad stride 130 (conflict-free b64 reads
    // at stride-2-float across lanes; staging writes land on distinct banks).
    __shared__ float Wt[64 * 130];            // 33280 B
    __shared__ float Hs[4][13 * 128];         // 26624 B  (per-wave jet state)

    const int tid  = threadIdx.x;
    const int wv   = tid >> 6;
    const int lane = tid & 63;
    const int pt   = (blockIdx.x << 2) + wv;  // one point per wave; grid exact

    const float x = xs[pt], y = ys[pt], tt = ts_[pt];
    float* hs = Hs[wv];

    float a0[13], a1[13];   // jets for this lane's two neurons n=2*lane, 2*lane+1

    // ---- layer 0: 3 -> 128 + tanh ----
    {
        const int n0 = 2 * lane, n1 = n0 + 1;
        float w00 = W0[n0 * 3 + 0], w01 = W0[n0 * 3 + 1], w02 = W0[n0 * 3 + 2];
        float w10 = W0[n1 * 3 + 0], w11 = W0[n1 * 3 + 1], w12 = W0[n1 * 3 + 2];
        #pragma unroll
        for (int c = 4; c < 13; ++c) { a0[c] = 0.f; a1[c] = 0.f; }
        a0[0] = w00 * x + w01 * y + w02 * tt + b0[n0];
        a0[1] = w00; a0[2] = w01; a0[3] = w02;
        a1[0] = w10 * x + w11 * y + w12 * tt + b0[n1];
        a1[1] = w10; a1[2] = w11; a1[3] = w12;
        tanh_jet(a0); tanh_jet(a1);
        #pragma unroll
        for (int c = 0; c < 13; ++c)
            ((float2*)(hs + c * 128))[lane] = make_float2(a0[c], a1[c]);
    }

    // ---- layers 1..7: 128 -> 128 + tanh (W staged in LDS, 64-col halves) ----
    for (int L = 0; L < 7; ++L) {
        const float* __restrict__ Wg = mw.W[L];
        #pragma unroll
        for (int c = 0; c < 13; ++c) { a0[c] = 0.f; a1[c] = 0.f; }

        for (int half = 0; half < 2; ++half) {
            __syncthreads();   // everyone done reading previous Wt contents
            // stage Wt[kk][n] = Wg[n][half*64+kk]; coalesced global reads
            #pragma unroll
            for (int r = 0; r < 32; ++r) {
                int idx = (r << 8) + tid;            // 0..8191
                int n   = idx >> 6;                  // 0..127
                int kk  = idx & 63;                  // 0..63
                Wt[kk * 130 + n] = Wg[n * 128 + (half << 6) + kk];
            }
            __syncthreads();

            const float* __restrict__ hrow = hs + (half << 6);
            for (int kk = 0; kk < 64; ++kk) {
                float2 w = ((const float2*)(Wt + kk * 130))[lane];  // W[2l,k],W[2l+1,k]
                #pragma unroll
                for (int c = 0; c < 13; ++c) {
                    float hk = hrow[c * 128 + kk];   // uniform broadcast
                    a0[c] = fmaf(w.x, hk, a0[c]);
                    a1[c] = fmaf(w.y, hk, a1[c]);
                }
            }
        }

        const float* __restrict__ bg = mw.b[L];
        a0[0] += bg[2 * lane];
        a1[0] += bg[2 * lane + 1];
        tanh_jet(a0); tanh_jet(a1);
        // per-wave private region; wave-internal program order makes this safe
        #pragma unroll
        for (int c = 0; c < 13; ++c)
            ((float2*)(hs + c * 128))[lane] = make_float2(a0[c], a1[c]);
    }

    // ---- final layer: 128 -> 2 (linear), wave reduction ----
    float pj[13], qj[3];
    {
        float wA0 = W8[2 * lane],       wA1 = W8[2 * lane + 1];        // psi row
        float wB0 = W8[128 + 2 * lane], wB1 = W8[128 + 2 * lane + 1];  // p row
        #pragma unroll
        for (int c = 0; c < 13; ++c) pj[c] = a0[c] * wA0 + a1[c] * wA1;
        #pragma unroll
        for (int c = 0; c < 3; ++c)  qj[c] = a0[c] * wB0 + a1[c] * wB1;
    }
    #pragma unroll
    for (int c = 0; c < 13; ++c) {
        float v = pj[c];
        #pragma unroll
        for (int off = 32; off > 0; off >>= 1) v += __shfl_xor(v, off);
        pj[c] = v;
    }
    #pragma unroll
    for (int c = 0; c < 3; ++c) {
        float v = qj[c];
        #pragma unroll
        for (int off = 32; off > 0; off >>= 1) v += __shfl_xor(v, off);
        qj[c] = v;
    }

    if (lane == 0) {
        // pj: psi jet (no bias needed for derivs; value unused), qj: p jet
        float l1 = l1p[0], l2 = l2p[0];
        float u   = pj[2];          // psi_y
        float v   = -pj[1];         // -psi_x
        float p   = qj[0] + b8[1];  // p value
        float u_t = pj[8];          // psi_yt
        float v_t = -pj[7];         // -psi_xt
        float u_x = pj[5];          // psi_xy
        float u_y = pj[6];          // psi_yy
        float v_x = -pj[4];         // -psi_xx
        float v_y = -pj[5];         // -psi_xy
        float u_xx = pj[10];        // psi_xxy
        float u_yy = pj[12];        // psi_yyy
        float v_xx = -pj[9];        // -psi_xxx
        float v_yy = -pj[11];       // -psi_xyy
        float p_x = qj[1], p_y = qj[2];
        float f_u = u_t + l1 * (u * u_x + v * u_y) + p_x - l2 * (u_xx + u_yy);
        float f_v = v_t + l1 * (u * v_x + v * v_y) + p_y - l2 * (v_xx + v_yy);
        out[0 * NPTS + pt] = u;
        out[1 * NPTS + pt] = v;
        out[2 * NPTS + pt] = p;
        out[3 * NPTS + pt] = f_u;
        out[4 * NPTS + pt] = f_v;
    }
}

extern "C" void kernel_launch(void* const* d_in, const int* in_sizes, int n_in,
                              void* d_out, int out_size, void* d_ws, size_t ws_size,
                              hipStream_t stream) {
    // setup_inputs() dict order: W0,b0,W1,b1,...,W8,b8, x, y, t, lambda_1, lambda_2
    const float* W0 = (const float*)d_in[0];
    const float* b0 = (const float*)d_in[1];
    MidW mw;
    for (int i = 0; i < 7; ++i) {
        mw.W[i] = (const float*)d_in[2 + 2 * i];
        mw.b[i] = (const float*)d_in[3 + 2 * i];
    }
    const float* W8 = (const float*)d_in[16];
    const float* b8 = (const float*)d_in[17];
    const float* xs = (const float*)d_in[18];
    const float* ys = (const float*)d_in[19];
    const float* ts = (const float*)d_in[20];
    const float* l1 = (const float*)d_in[21];
    const float* l2 = (const float*)d_in[22];

    pinn_jet_kernel<<<NPTS / 4, 256, 0, stream>>>(
        W0, b0, mw, W8, b8, xs, ys, ts, l1, l2, (float*)d_out);
}

// Round 2
// 428.215 us; speedup vs baseline: 1.8168x; 1.8168x over previous
//
#include <hip/hip_runtime.h>
#include <stdint.h>

#define NPTS 16384

typedef __attribute__((ext_vector_type(8)))  __bf16   bf16x8;
typedef __attribute__((ext_vector_type(16))) float    f32x16;
typedef __attribute__((ext_vector_type(4)))  uint32_t u32x4;

struct Args {
    const float* W[9];
    const float* b[9];
    const float* xs;
    const float* ys;
    const float* ts;
    const float* l1;
    const float* l2;
    float* out;
};

// ---------- bf16 split helpers ----------
__device__ __forceinline__ uint32_t b16rne(float x) {
    uint32_t u = __float_as_uint(x);
    return (u + 0x7FFFu + ((u >> 16) & 1u)) >> 16;
}
__device__ __forceinline__ float fromb16(uint32_t h) { return __uint_as_float(h << 16); }

// packed A word: hi bf16 in high 16, lo bf16 in low 16
__device__ __forceinline__ uint32_t packA(float x) {
    uint32_t h = b16rne(x);
    float lo = x - fromb16(h);
    return (h << 16) | b16rne(lo);
}
// W pair: two consecutive-k elems -> one hi word (elem order low-first) + one lo word
__device__ __forceinline__ void packW2(float u, float v, uint32_t& hw, uint32_t& lw) {
    uint32_t hu = b16rne(u), hv = b16rne(v);
    float lu = u - fromb16(hu), lv = v - fromb16(hv);
    hw = hu | (hv << 16);
    lw = b16rne(lu) | (b16rne(lv) << 16);
}

// unpack 8 packed A words (2x u32x4) into hi-frag / lo-frag bf16x8
__device__ __forceinline__ void unpackA(u32x4 wa, u32x4 wb, bf16x8& hi, bf16x8& lo) {
    u32x4 h, l;
    h[0] = __builtin_amdgcn_perm(wa[1], wa[0], 0x07060302u);
    h[1] = __builtin_amdgcn_perm(wa[3], wa[2], 0x07060302u);
    h[2] = __builtin_amdgcn_perm(wb[1], wb[0], 0x07060302u);
    h[3] = __builtin_amdgcn_perm(wb[3], wb[2], 0x07060302u);
    l[0] = __builtin_amdgcn_perm(wa[1], wa[0], 0x05040100u);
    l[1] = __builtin_amdgcn_perm(wa[3], wa[2], 0x05040100u);
    l[2] = __builtin_amdgcn_perm(wb[1], wb[0], 0x05040100u);
    l[3] = __builtin_amdgcn_perm(wb[3], wb[2], 0x05040100u);
    hi = __builtin_bit_cast(bf16x8, h);
    lo = __builtin_bit_cast(bf16x8, l);
}

__device__ __forceinline__ f32x16 mfma16(bf16x8 a, bf16x8 b, f32x16 c) {
    return __builtin_amdgcn_mfma_f32_32x32x16_bf16(a, b, c, 0, 0, 0);
}

// ---------- tanh jet (verified round 1) ----------
// 0:val 1:dx 2:dy 3:dt 4:dxx 5:dxy 6:dyy 7:dxt 8:dyt 9:dxxx 10:dxxy 11:dxyy 12:dyyy
__device__ __forceinline__ void tanh_jet(float u[13]) {
    float s    = tanhf(u[0]);
    float sp   = 1.f - s * s;
    float spp  = -2.f * s * sp;
    float sppp = -2.f * (sp * sp + s * spp);
    float u1 = u[1], u2 = u[2], u3 = u[3];
    float u4 = u[4], u5 = u[5], u6 = u[6];
    u[0] = s;
    u[1] = sp * u1;
    u[2] = sp * u2;
    u[3] = sp * u3;
    u[9]  = sppp * u1 * u1 * u1 + 3.f * spp * u1 * u4 + sp * u[9];
    u[10] = sppp * u1 * u1 * u2 + spp * (u4 * u2 + 2.f * u5 * u1) + sp * u[10];
    u[11] = sppp * u1 * u2 * u2 + spp * (u6 * u1 + 2.f * u5 * u2) + sp * u[11];
    u[12] = sppp * u2 * u2 * u2 + 3.f * spp * u2 * u6 + sp * u[12];
    u[4] = spp * u1 * u1 + sp * u4;
    u[5] = spp * u1 * u2 + sp * u5;
    u[6] = spp * u2 * u2 + sp * u6;
    u[7] = spp * u1 * u3 + sp * u[7];
    u[8] = spp * u2 * u3 + sp * u[8];
}

// Layout:
//   Abuf: packed jet activations, word[row*128 + (k ^ ((row&7)<<2))], row = c*8 + p
//         (rows 104..127 = pad channels, zeroed once)
//   WDbuf: per layer, first W frag-order (hi words [0..8191], lo words [8192..16383]):
//         (kb,n) -> 4 words at (kb*128+n)*4, holding bf16 of W[n][kb*8 + j], j=0..7
//         then aliased as D[row*128 + col] fp32 after the GEMM.
__global__ __launch_bounds__(256, 1)
void pinn_mfma_kernel(Args args)
{
    __shared__ uint32_t Abuf[16384];   // 64 KB
    __shared__ uint32_t WDbuf[16384];  // 64 KB (W staging / D, aliased)
    float* Df = (float*)WDbuf;

    const int tid  = threadIdx.x;
    const int lane = tid & 63;
    const int wid  = tid >> 6;
    const int ln31 = lane & 31;
    const int kh   = lane >> 5;
    const int p    = tid >> 5;        // job-phase point 0..7
    const int jn0  = tid & 31;        // job-phase n lane
    const int pt   = blockIdx.x * 8 + p;

    // ---- prefetch W1 into regs (hides HBM latency under layer-0 compute) ----
    float4 pf[16];
    {
        const float* Wsrc = args.W[1];
        #pragma unroll
        for (int jj = 0; jj < 8; ++jj) {
            int g = tid + 256 * jj;
            int n = g & 127, kb = g >> 7;
            const float4* s = (const float4*)(Wsrc + n * 128 + kb * 8);
            pf[2 * jj]     = s[0];
            pf[2 * jj + 1] = s[1];
        }
    }

    // ---- layer 0: 3 -> 128, jets from closed form ----
    {
        const float x = args.xs[pt], y = args.ys[pt], t = args.ts[pt];
        #pragma unroll
        for (int jj = 0; jj < 4; ++jj) {
            int n = jn0 + 32 * jj;
            float w0 = args.W[0][n * 3 + 0], w1 = args.W[0][n * 3 + 1], w2 = args.W[0][n * 3 + 2];
            float d[13];
            d[0] = w0 * x + w1 * y + w2 * t + args.b[0][n];
            d[1] = w0; d[2] = w1; d[3] = w2;
            #pragma unroll
            for (int c = 4; c < 13; ++c) d[c] = 0.f;
            tanh_jet(d);
            #pragma unroll
            for (int c = 0; c < 13; ++c) {
                int row = c * 8 + p;
                Abuf[row * 128 + (n ^ ((row & 7) << 2))] = packA(d[c]);
            }
        }
        for (int i = tid; i < 24 * 128; i += 256) Abuf[104 * 128 + i] = 0;
    }

    // ---- stage W1 into LDS ----
    #pragma unroll
    for (int jj = 0; jj < 8; ++jj) {
        int g = tid + 256 * jj;
        int n = g & 127, kb = g >> 7;
        float4 a = pf[2 * jj], bq = pf[2 * jj + 1];
        uint32_t h0, h1, h2, h3, l0w, l1w, l2w, l3w;
        packW2(a.x,  a.y,  h0, l0w);
        packW2(a.z,  a.w,  h1, l1w);
        packW2(bq.x, bq.y, h2, l2w);
        packW2(bq.z, bq.w, h3, l3w);
        int base = (kb * 128 + n) * 4;
        *(u32x4*)&WDbuf[base]        = u32x4{h0, h1, h2, h3};
        *(u32x4*)&WDbuf[8192 + base] = u32x4{l0w, l1w, l2w, l3w};
    }
    __syncthreads();

    // ---- wave tile assignment: 2x2 waves, each 64x64 output ----
    const int rtb   = (wid >> 1) * 64;
    const int ctb   = (wid & 1) * 64;
    const int arow0 = (rtb + ln31) * 128;
    const int arow1 = (rtb + 32 + ln31) * 128;
    const int sw    = (ln31 & 7) << 2;

    float pj[13], qj[3];

    for (int L = 1; L <= 7; ++L) {
        f32x16 acc00{}, acc01{}, acc10{}, acc11{};

        #pragma unroll
        for (int ks = 0; ks < 8; ++ks) {
            int k0 = ks * 16 + kh * 8;
            int e0 = k0 ^ sw, e1 = (k0 + 4) ^ sw;
            u32x4 wa0  = *(const u32x4*)&Abuf[arow0 + e0];
            u32x4 wa0b = *(const u32x4*)&Abuf[arow0 + e1];
            u32x4 wa1  = *(const u32x4*)&Abuf[arow1 + e0];
            u32x4 wa1b = *(const u32x4*)&Abuf[arow1 + e1];
            bf16x8 ahi0, alo0, ahi1, alo1;
            unpackA(wa0, wa0b, ahi0, alo0);
            unpackA(wa1, wa1b, ahi1, alo1);

            int kb   = ks * 2 + kh;
            int bidx = (kb * 128 + ctb + ln31) * 4;
            bf16x8 bhi0 = __builtin_bit_cast(bf16x8, *(const u32x4*)&WDbuf[bidx]);
            bf16x8 blo0 = __builtin_bit_cast(bf16x8, *(const u32x4*)&WDbuf[8192 + bidx]);
            bf16x8 bhi1 = __builtin_bit_cast(bf16x8, *(const u32x4*)&WDbuf[bidx + 128]);
            bf16x8 blo1 = __builtin_bit_cast(bf16x8, *(const u32x4*)&WDbuf[8192 + bidx + 128]);

            acc00 = mfma16(ahi0, bhi0, acc00);
            acc10 = mfma16(ahi1, bhi0, acc10);
            acc01 = mfma16(ahi0, bhi1, acc01);
            acc11 = mfma16(ahi1, bhi1, acc11);
            acc00 = mfma16(alo0, bhi0, acc00);
            acc10 = mfma16(alo1, bhi0, acc10);
            acc01 = mfma16(alo0, bhi1, acc01);
            acc11 = mfma16(alo1, bhi1, acc11);
            acc00 = mfma16(ahi0, blo0, acc00);
            acc10 = mfma16(ahi1, blo0, acc10);
            acc01 = mfma16(ahi0, blo1, acc01);
            acc11 = mfma16(ahi1, blo1, acc11);
        }

        // prefetch next layer's W while D/tanh phases run
        if (L < 7) {
            const float* Wsrc = args.W[L + 1];
            #pragma unroll
            for (int jj = 0; jj < 8; ++jj) {
                int g = tid + 256 * jj;
                int n = g & 127, kb = g >> 7;
                const float4* s = (const float4*)(Wsrc + n * 128 + kb * 8);
                pf[2 * jj]     = s[0];
                pf[2 * jj + 1] = s[1];
            }
        }

        __syncthreads();   // GEMM done reading A and W

        // ---- dump acc -> D (fp32) ----
        {
            const int colb = ctb + ln31;
            #pragma unroll
            for (int i = 0; i < 16; ++i) {
                int r0 = rtb + (i & 3) + 8 * (i >> 2) + 4 * kh;
                Df[r0 * 128 + colb]             = acc00[i];
                Df[(r0 + 32) * 128 + colb]      = acc10[i];
                Df[r0 * 128 + colb + 32]        = acc01[i];
                Df[(r0 + 32) * 128 + colb + 32] = acc11[i];
            }
        }
        __syncthreads();

        // ---- tanh-jet phase (jobs: point p, neurons n = jn0 + 32*jj) ----
        if (L == 7) {
            #pragma unroll
            for (int c = 0; c < 13; ++c) pj[c] = 0.f;
            qj[0] = qj[1] = qj[2] = 0.f;
        }
        #pragma unroll
        for (int jj = 0; jj < 4; ++jj) {
            int n = jn0 + 32 * jj;
            float d[13];
            #pragma unroll
            for (int c = 0; c < 13; ++c) d[c] = Df[(c * 8 + p) * 128 + n];
            d[0] += args.b[L][n];
            tanh_jet(d);
            if (L < 7) {
                #pragma unroll
                for (int c = 0; c < 13; ++c) {
                    int row = c * 8 + p;
                    Abuf[row * 128 + (n ^ ((row & 7) << 2))] = packA(d[c]);
                }
            } else {
                float wpsi = args.W[8][n], wp = args.W[8][128 + n];
                #pragma unroll
                for (int c = 0; c < 13; ++c) pj[c] += wpsi * d[c];
                qj[0] += wp * d[0];
                qj[1] += wp * d[1];
                qj[2] += wp * d[2];
            }
        }

        if (L < 7) {
            __syncthreads();   // all tanh jobs done reading D
            #pragma unroll
            for (int jj = 0; jj < 8; ++jj) {
                int g = tid + 256 * jj;
                int n = g & 127, kb = g >> 7;
                float4 a = pf[2 * jj], bq = pf[2 * jj + 1];
                uint32_t h0, h1, h2, h3, l0w, l1w, l2w, l3w;
                packW2(a.x,  a.y,  h0, l0w);
                packW2(a.z,  a.w,  h1, l1w);
                packW2(bq.x, bq.y, h2, l2w);
                packW2(bq.z, bq.w, h3, l3w);
                int base = (kb * 128 + n) * 4;
                *(u32x4*)&WDbuf[base]        = u32x4{h0, h1, h2, h3};
                *(u32x4*)&WDbuf[8192 + base] = u32x4{l0w, l1w, l2w, l3w};
            }
            __syncthreads();   // A + W ready for next layer
        }
    }

    // ---- final reduce over 32-lane groups and output ----
    #pragma unroll
    for (int c = 0; c < 13; ++c) {
        float v = pj[c];
        v += __shfl_xor(v, 16); v += __shfl_xor(v, 8); v += __shfl_xor(v, 4);
        v += __shfl_xor(v, 2);  v += __shfl_xor(v, 1);
        pj[c] = v;
    }
    #pragma unroll
    for (int c = 0; c < 3; ++c) {
        float v = qj[c];
        v += __shfl_xor(v, 16); v += __shfl_xor(v, 8); v += __shfl_xor(v, 4);
        v += __shfl_xor(v, 2);  v += __shfl_xor(v, 1);
        qj[c] = v;
    }

    if (jn0 == 0) {
        float l1 = args.l1[0], l2 = args.l2[0];
        float u    = pj[2];            // psi_y
        float v    = -pj[1];           // -psi_x
        float pv   = qj[0] + args.b[8][1];
        float u_t  = pj[8];            // psi_yt
        float v_t  = -pj[7];           // -psi_xt
        float u_x  = pj[5];            // psi_xy
        float u_y  = pj[6];            // psi_yy
        float v_x  = -pj[4];           // -psi_xx
        float v_y  = -pj[5];           // -psi_xy
        float u_xx = pj[10];           // psi_xxy
        float u_yy = pj[12];           // psi_yyy
        float v_xx = -pj[9];           // -psi_xxx
        float v_yy = -pj[11];          // -psi_xyy
        float p_x = qj[1], p_y = qj[2];
        float f_u = u_t + l1 * (u * u_x + v * u_y) + p_x - l2 * (u_xx + u_yy);
        float f_v = v_t + l1 * (u * v_x + v * v_y) + p_y - l2 * (v_xx + v_yy);
        float* out = args.out;
        out[0 * NPTS + pt] = u;
        out[1 * NPTS + pt] = v;
        out[2 * NPTS + pt] = pv;
        out[3 * NPTS + pt] = f_u;
        out[4 * NPTS + pt] = f_v;
    }
}

extern "C" void kernel_launch(void* const* d_in, const int* in_sizes, int n_in,
                              void* d_out, int out_size, void* d_ws, size_t ws_size,
                              hipStream_t stream) {
    Args a;
    for (int i = 0; i < 9; ++i) {
        a.W[i] = (const float*)d_in[2 * i];
        a.b[i] = (const float*)d_in[2 * i + 1];
    }
    a.xs  = (const float*)d_in[18];
    a.ys  = (const float*)d_in[19];
    a.ts  = (const float*)d_in[20];
    a.l1  = (const float*)d_in[21];
    a.l2  = (const float*)d_in[22];
    a.out = (float*)d_out;

    pinn_mfma_kernel<<<NPTS / 8, 256, 0, stream>>>(a);
}

// Round 4
// 232.808 us; speedup vs baseline: 3.3417x; 1.8393x over previous
//
#include <hip/hip_runtime.h>
#include <stdint.h>

#define NPTS 16384

typedef __attribute__((ext_vector_type(8)))  __bf16   bf16x8;
typedef __attribute__((ext_vector_type(16))) float    f32x16;
typedef __attribute__((ext_vector_type(4)))  uint32_t u32x4;

struct PrepArgs { const float* W[7]; u32x4* dst; };

struct Args {
    const float* W0; const float* b0;
    const float* bias[8];   // [1..7] valid
    const float* W8; const float* b8;
    const float* xs; const float* ys; const float* ts;
    const float* l1; const float* l2;
    const u32x4* wpk;       // packed W frags in d_ws
    float* out;
};

// ---------- bf16 split helpers (round-2 verified) ----------
__device__ __forceinline__ uint32_t b16rne(float x) {
    uint32_t u = __float_as_uint(x);
    return (u + 0x7FFFu + ((u >> 16) & 1u)) >> 16;
}
__device__ __forceinline__ float fromb16(uint32_t h) { return __uint_as_float(h << 16); }

// packed A word: hi bf16 in HIGH 16, lo bf16 in LOW 16 (round-2 format)
__device__ __forceinline__ uint32_t packA(float x) {
    uint32_t h = b16rne(x);
    float lo = x - fromb16(h);
    return (h << 16) | b16rne(lo);
}
// W pair: hi word (earlier-k in low 16) + lo word (round-2 format)
__device__ __forceinline__ void packPair(float a, float b, uint32_t& hw, uint32_t& lw) {
    uint32_t ha = b16rne(a), hb = b16rne(b);
    float la = a - fromb16(ha), lb = b - fromb16(hb);
    hw = ha | (hb << 16);
    lw = b16rne(la) | (b16rne(lb) << 16);
}

// unpack 8 packed A words (2x u32x4) into hi-frag / lo-frag (round-2 verbatim)
__device__ __forceinline__ void unpackA(u32x4 wa, u32x4 wb, bf16x8& hi, bf16x8& lo) {
    u32x4 h, l;
    h[0] = __builtin_amdgcn_perm(wa[1], wa[0], 0x07060302u);
    h[1] = __builtin_amdgcn_perm(wa[3], wa[2], 0x07060302u);
    h[2] = __builtin_amdgcn_perm(wb[1], wb[0], 0x07060302u);
    h[3] = __builtin_amdgcn_perm(wb[3], wb[2], 0x07060302u);
    l[0] = __builtin_amdgcn_perm(wa[1], wa[0], 0x05040100u);
    l[1] = __builtin_amdgcn_perm(wa[3], wa[2], 0x05040100u);
    l[2] = __builtin_amdgcn_perm(wb[1], wb[0], 0x05040100u);
    l[3] = __builtin_amdgcn_perm(wb[3], wb[2], 0x05040100u);
    hi = __builtin_bit_cast(bf16x8, h);
    lo = __builtin_bit_cast(bf16x8, l);
}

__device__ __forceinline__ f32x16 mfma16(bf16x8 a, bf16x8 b, f32x16 c) {
    return __builtin_amdgcn_mfma_f32_32x32x16_bf16(a, b, c, 0, 0, 0);
}

// ---------- tanh jet (tanhf restored) ----------
// 0:val 1:dx 2:dy 3:dt 4:dxx 5:dxy 6:dyy 7:dxt 8:dyt 9:dxxx 10:dxxy 11:dxyy 12:dyyy
__device__ __forceinline__ void tanh_jet(float u[13]) {
    float s    = tanhf(u[0]);
    float sp   = 1.f - s * s;
    float spp  = -2.f * s * sp;
    float sppp = -2.f * (sp * sp + s * spp);
    float u1 = u[1], u2 = u[2], u3 = u[3];
    float u4 = u[4], u5 = u[5], u6 = u[6];
    u[0] = s;
    u[1] = sp * u1;
    u[2] = sp * u2;
    u[3] = sp * u3;
    u[9]  = sppp * u1 * u1 * u1 + 3.f * spp * u1 * u4 + sp * u[9];
    u[10] = sppp * u1 * u1 * u2 + spp * (u4 * u2 + 2.f * u5 * u1) + sp * u[10];
    u[11] = sppp * u1 * u2 * u2 + spp * (u6 * u1 + 2.f * u5 * u2) + sp * u[11];
    u[12] = sppp * u2 * u2 * u2 + 3.f * spp * u2 * u6 + sp * u[12];
    u[4] = spp * u1 * u1 + sp * u4;
    u[5] = spp * u1 * u2 + sp * u5;
    u[6] = spp * u2 * u2 + sp * u6;
    u[7] = spp * u1 * u3 + sp * u[7];
    u[8] = spp * u2 * u3 + sp * u[8];
}

// ---------- prep: pack W1..W7 into B-frag order (hi plane, lo plane) ----------
// dst[((L*2+h)*16 + kb)*128 + n] = u32x4 of bf16 pairs W[n][kb*8 + 0..7]
__global__ __launch_bounds__(256)
void pack_w_kernel(PrepArgs a) {
    int idx = blockIdx.x * 256 + threadIdx.x;   // 7*16*128 = 14336
    int L  = idx >> 11;
    int kb = (idx >> 7) & 15;
    int n  = idx & 127;
    const float* w = a.W[L] + n * 128 + kb * 8;
    float4 f0 = *(const float4*)w;
    float4 f1 = *(const float4*)(w + 4);
    uint32_t h0, h1, h2, h3, l0, l1, l2, l3;
    packPair(f0.x, f0.y, h0, l0);
    packPair(f0.z, f0.w, h1, l1);
    packPair(f1.x, f1.y, h2, l2);
    packPair(f1.z, f1.w, h3, l3);
    a.dst[((L * 2 + 0) * 16 + kb) * 128 + n] = u32x4{h0, h1, h2, h3};
    a.dst[((L * 2 + 1) * 16 + kb) * 128 + n] = u32x4{l0, l1, l2, l3};
}

// ---------- main ----------
// M=64 rows: row = c*4 + p (13 channels x 4 points), rows 52..63 pad (zeroed once).
// Abuf (round-2 format): word[row*128 + (n ^ ((row&7)<<2))], 32 KB.
// Dbuf: separate fp32 [64][128], 32 KB. No aliasing anywhere.
__global__ __launch_bounds__(256, 2)
void pinn_mfma3_kernel(Args args)
{
    __shared__ uint32_t Abuf[64 * 128];  // 32 KB
    __shared__ float    Dbuf[64 * 128];  // 32 KB

    const int tid  = threadIdx.x;
    const int lane = tid & 63;
    const int wid  = tid >> 6;
    const int ln31 = lane & 31;
    const int kh   = lane >> 5;
    const int p    = wid;              // one point per wave (tanh/jet phases)
    const int n0   = 2 * lane;         // this thread's neuron pair
    const int pt   = blockIdx.x * 4 + p;

    // ---- layer 0: 3 -> 128, jets closed-form ----
    {
        const float x = args.xs[pt], y = args.ys[pt], t = args.ts[pt];
        float d0[13], d1[13];
        float w00 = args.W0[n0 * 3],     w01 = args.W0[n0 * 3 + 1], w02 = args.W0[n0 * 3 + 2];
        float w10 = args.W0[n0 * 3 + 3], w11 = args.W0[n0 * 3 + 4], w12 = args.W0[n0 * 3 + 5];
        #pragma unroll
        for (int c = 4; c < 13; ++c) { d0[c] = 0.f; d1[c] = 0.f; }
        d0[0] = w00 * x + w01 * y + w02 * t + args.b0[n0];
        d0[1] = w00; d0[2] = w01; d0[3] = w02;
        d1[0] = w10 * x + w11 * y + w12 * t + args.b0[n0 + 1];
        d1[1] = w10; d1[2] = w11; d1[3] = w12;
        tanh_jet(d0); tanh_jet(d1);
        #pragma unroll
        for (int c = 0; c < 13; ++c) {
            int row = c * 4 + p;
            int swr = (row & 7) << 2;
            Abuf[row * 128 + (n0 ^ swr)]       = packA(d0[c]);
            Abuf[row * 128 + ((n0 + 1) ^ swr)] = packA(d1[c]);
        }
        // zero pad rows 52..63 once; Dbuf is separate so pads stay zero forever
        #pragma unroll
        for (int i = 0; i < 6; ++i) {
            int idx = tid + 256 * i;           // 12 rows * 128 words = 1536
            Abuf[52 * 128 + idx] = 0;
        }
    }
    __syncthreads();

    // ---- GEMM wave tiles: wave wid owns cols ctb..ctb+31, all 64 rows ----
    const int ctb = wid * 32;
    float pj[13], qj[3];

    for (int L = 1; L <= 7; ++L) {
        const u32x4* whi = args.wpk + (size_t)(L - 1) * 4096;
        const u32x4* wlo = whi + 2048;
        f32x16 acc0{}, acc1{};

        #pragma unroll
        for (int ks = 0; ks < 8; ++ks) {
            const int kb = ks * 2 + kh;
            u32x4 rbh = whi[kb * 128 + ctb + ln31];
            u32x4 rbl = wlo[kb * 128 + ctb + ln31];

            const int k0 = ks * 16 + kh * 8;
            const int sw = (ln31 & 7) << 2;
            const int e0 = k0 ^ sw, e1 = (k0 + 4) ^ sw;
            const int arow0 = ln31 * 128, arow1 = (32 + ln31) * 128;
            u32x4 wa0  = *(const u32x4*)&Abuf[arow0 + e0];
            u32x4 wa0b = *(const u32x4*)&Abuf[arow0 + e1];
            u32x4 wa1  = *(const u32x4*)&Abuf[arow1 + e0];
            u32x4 wa1b = *(const u32x4*)&Abuf[arow1 + e1];
            bf16x8 ah0, al0, ah1, al1;
            unpackA(wa0, wa0b, ah0, al0);
            unpackA(wa1, wa1b, ah1, al1);

            bf16x8 bh = __builtin_bit_cast(bf16x8, rbh);
            bf16x8 bl = __builtin_bit_cast(bf16x8, rbl);

            acc0 = mfma16(ah0, bh, acc0);
            acc1 = mfma16(ah1, bh, acc1);
            acc0 = mfma16(al0, bh, acc0);
            acc1 = mfma16(al1, bh, acc1);
            acc0 = mfma16(ah0, bl, acc0);
            acc1 = mfma16(ah1, bl, acc1);
        }

        __syncthreads();   // all waves done reading A (safe to rewrite A later)

        // ---- dump acc -> D ----
        {
            const int colb = ctb + ln31;
            #pragma unroll
            for (int i = 0; i < 16; ++i) {
                int r = (i & 3) + 8 * (i >> 2) + 4 * kh;
                Dbuf[r * 128 + colb]        = acc0[i];
                Dbuf[(r + 32) * 128 + colb] = acc1[i];
            }
        }
        __syncthreads();   // D visible to all

        // ---- tanh-jet phase: thread (p=wid, neurons n0,n0+1) ----
        float d0[13], d1[13];
        #pragma unroll
        for (int c = 0; c < 13; ++c) {
            float2 va = *(const float2*)&Dbuf[(c * 4 + p) * 128 + n0];
            d0[c] = va.x; d1[c] = va.y;
        }
        const float* bL = args.bias[L];
        d0[0] += bL[n0];
        d1[0] += bL[n0 + 1];
        tanh_jet(d0); tanh_jet(d1);

        if (L < 7) {
            // writes go to Abuf (disjoint from Dbuf); GEMM A-reads ended at sync above
            #pragma unroll
            for (int c = 0; c < 13; ++c) {
                int row = c * 4 + p;
                int swr = (row & 7) << 2;
                Abuf[row * 128 + (n0 ^ swr)]       = packA(d0[c]);
                Abuf[row * 128 + ((n0 + 1) ^ swr)] = packA(d1[c]);
            }
            __syncthreads();   // A ready for next layer
        } else {
            float wpsi0 = args.W8[n0],       wpsi1 = args.W8[n0 + 1];
            float wp0   = args.W8[128 + n0], wp1   = args.W8[128 + n0 + 1];
            #pragma unroll
            for (int c = 0; c < 13; ++c) pj[c] = wpsi0 * d0[c] + wpsi1 * d1[c];
            #pragma unroll
            for (int c = 0; c < 3; ++c)  qj[c] = wp0 * d0[c] + wp1 * d1[c];
        }
    }

    // ---- full-wave (64-lane) reduce and emit ----
    #pragma unroll
    for (int c = 0; c < 13; ++c) {
        float v = pj[c];
        v += __shfl_xor(v, 32); v += __shfl_xor(v, 16); v += __shfl_xor(v, 8);
        v += __shfl_xor(v, 4);  v += __shfl_xor(v, 2);  v += __shfl_xor(v, 1);
        pj[c] = v;
    }
    #pragma unroll
    for (int c = 0; c < 3; ++c) {
        float v = qj[c];
        v += __shfl_xor(v, 32); v += __shfl_xor(v, 16); v += __shfl_xor(v, 8);
        v += __shfl_xor(v, 4);  v += __shfl_xor(v, 2);  v += __shfl_xor(v, 1);
        qj[c] = v;
    }

    if (lane == 0) {
        float l1 = args.l1[0], l2 = args.l2[0];
        float u    = pj[2];            // psi_y
        float v    = -pj[1];           // -psi_x
        float pv   = qj[0] + args.b8[1];
        float u_t  = pj[8];            // psi_yt
        float v_t  = -pj[7];           // -psi_xt
        float u_x  = pj[5];            // psi_xy
        float u_y  = pj[6];            // psi_yy
        float v_x  = -pj[4];           // -psi_xx
        float v_y  = -pj[5];           // -psi_xy
        float u_xx = pj[10];           // psi_xxy
        float u_yy = pj[12];           // psi_yyy
        float v_xx = -pj[9];           // -psi_xxx
        float v_yy = -pj[11];          // -psi_xyy
        float p_x = qj[1], p_y = qj[2];
        float f_u = u_t + l1 * (u * u_x + v * u_y) + p_x - l2 * (u_xx + u_yy);
        float f_v = v_t + l1 * (u * v_x + v * v_y) + p_y - l2 * (v_xx + v_yy);
        float* out = args.out;
        out[0 * NPTS + pt] = u;
        out[1 * NPTS + pt] = v;
        out[2 * NPTS + pt] = pv;
        out[3 * NPTS + pt] = f_u;
        out[4 * NPTS + pt] = f_v;
    }
}

extern "C" void kernel_launch(void* const* d_in, const int* in_sizes, int n_in,
                              void* d_out, int out_size, void* d_ws, size_t ws_size,
                              hipStream_t stream) {
    PrepArgs pa;
    for (int i = 0; i < 7; ++i) pa.W[i] = (const float*)d_in[2 * (i + 1)];
    pa.dst = (u32x4*)d_ws;   // 7*2*16*128*16B = 448 KB
    pack_w_kernel<<<56, 256, 0, stream>>>(pa);

    Args a;
    a.W0 = (const float*)d_in[0];
    a.b0 = (const float*)d_in[1];
    a.bias[0] = nullptr;
    for (int L = 1; L <= 7; ++L) a.bias[L] = (const float*)d_in[2 * L + 1];
    a.W8 = (const float*)d_in[16];
    a.b8 = (const float*)d_in[17];
    a.xs = (const float*)d_in[18];
    a.ys = (const float*)d_in[19];
    a.ts = (const float*)d_in[20];
    a.l1 = (const float*)d_in[21];
    a.l2 = (const float*)d_in[22];
    a.wpk = (const u32x4*)d_ws;
    a.out = (float*)d_out;

    pinn_mfma3_kernel<<<NPTS / 4, 256, 0, stream>>>(a);
}

// Round 5
// 207.063 us; speedup vs baseline: 3.7572x; 1.1243x over previous
//
#include <hip/hip_runtime.h>
#include <stdint.h>

#define NPTS 16384

typedef __attribute__((ext_vector_type(8)))  __bf16   bf16x8;
typedef __attribute__((ext_vector_type(16))) float    f32x16;
typedef __attribute__((ext_vector_type(4)))  uint32_t u32x4;

struct PrepArgs { const float* W[7]; u32x4* dst; };

struct Args {
    const float* W0; const float* b0;
    const float* bias[8];   // [1..7] valid
    const float* W8; const float* b8;
    const float* xs; const float* ys; const float* ts;
    const float* l1; const float* l2;
    const u32x4* wpk;       // packed W frags in d_ws
    float* out;
};

// ---------- bf16 split helpers (round-2/4 verified) ----------
__device__ __forceinline__ uint32_t b16rne(float x) {
    uint32_t u = __float_as_uint(x);
    return (u + 0x7FFFu + ((u >> 16) & 1u)) >> 16;
}
__device__ __forceinline__ float fromb16(uint32_t h) { return __uint_as_float(h << 16); }

// packed A word: hi bf16 in HIGH 16, lo bf16 in LOW 16
__device__ __forceinline__ uint32_t packA(float x) {
    uint32_t h = b16rne(x);
    float lo = x - fromb16(h);
    return (h << 16) | b16rne(lo);
}
// W pair: hi word (earlier-k in low 16) + lo word
__device__ __forceinline__ void packPair(float a, float b, uint32_t& hw, uint32_t& lw) {
    uint32_t ha = b16rne(a), hb = b16rne(b);
    float la = a - fromb16(ha), lb = b - fromb16(hb);
    hw = ha | (hb << 16);
    lw = b16rne(la) | (b16rne(lb) << 16);
}

// unpack 8 packed A words (2x u32x4) into hi-frag / lo-frag (round-2/4 verbatim)
__device__ __forceinline__ void unpackA(u32x4 wa, u32x4 wb, bf16x8& hi, bf16x8& lo) {
    u32x4 h, l;
    h[0] = __builtin_amdgcn_perm(wa[1], wa[0], 0x07060302u);
    h[1] = __builtin_amdgcn_perm(wa[3], wa[2], 0x07060302u);
    h[2] = __builtin_amdgcn_perm(wb[1], wb[0], 0x07060302u);
    h[3] = __builtin_amdgcn_perm(wb[3], wb[2], 0x07060302u);
    l[0] = __builtin_amdgcn_perm(wa[1], wa[0], 0x05040100u);
    l[1] = __builtin_amdgcn_perm(wa[3], wa[2], 0x05040100u);
    l[2] = __builtin_amdgcn_perm(wb[1], wb[0], 0x05040100u);
    l[3] = __builtin_amdgcn_perm(wb[3], wb[2], 0x05040100u);
    hi = __builtin_bit_cast(bf16x8, h);
    lo = __builtin_bit_cast(bf16x8, l);
}

__device__ __forceinline__ f32x16 mfma16(bf16x8 a, bf16x8 b, f32x16 c) {
    return __builtin_amdgcn_mfma_f32_32x32x16_bf16(a, b, c, 0, 0, 0);
}

// ---------- tanh jet (round-4 verified) ----------
// 0:val 1:dx 2:dy 3:dt 4:dxx 5:dxy 6:dyy 7:dxt 8:dyt 9:dxxx 10:dxxy 11:dxyy 12:dyyy
__device__ __forceinline__ void tanh_jet(float u[13]) {
    float s    = tanhf(u[0]);
    float sp   = 1.f - s * s;
    float spp  = -2.f * s * sp;
    float sppp = -2.f * (sp * sp + s * spp);
    float u1 = u[1], u2 = u[2], u3 = u[3];
    float u4 = u[4], u5 = u[5], u6 = u[6];
    u[0] = s;
    u[1] = sp * u1;
    u[2] = sp * u2;
    u[3] = sp * u3;
    u[9]  = sppp * u1 * u1 * u1 + 3.f * spp * u1 * u4 + sp * u[9];
    u[10] = sppp * u1 * u1 * u2 + spp * (u4 * u2 + 2.f * u5 * u1) + sp * u[10];
    u[11] = sppp * u1 * u2 * u2 + spp * (u6 * u1 + 2.f * u5 * u2) + sp * u[11];
    u[12] = sppp * u2 * u2 * u2 + 3.f * spp * u2 * u6 + sp * u[12];
    u[4] = spp * u1 * u1 + sp * u4;
    u[5] = spp * u1 * u2 + sp * u5;
    u[6] = spp * u2 * u2 + sp * u6;
    u[7] = spp * u1 * u3 + sp * u[7];
    u[8] = spp * u2 * u3 + sp * u[8];
}

// ---------- prep: pack W1..W7 into B-frag order (verified) ----------
__global__ __launch_bounds__(256)
void pack_w_kernel(PrepArgs a) {
    int idx = blockIdx.x * 256 + threadIdx.x;   // 7*16*128 = 14336
    int L  = idx >> 11;
    int kb = (idx >> 7) & 15;
    int n  = idx & 127;
    const float* w = a.W[L] + n * 128 + kb * 8;
    float4 f0 = *(const float4*)w;
    float4 f1 = *(const float4*)(w + 4);
    uint32_t h0, h1, h2, h3, l0, l1, l2, l3;
    packPair(f0.x, f0.y, h0, l0);
    packPair(f0.z, f0.w, h1, l1);
    packPair(f1.x, f1.y, h2, l2);
    packPair(f1.z, f1.w, h3, l3);
    a.dst[((L * 2 + 0) * 16 + kb) * 128 + n] = u32x4{h0, h1, h2, h3};
    a.dst[((L * 2 + 1) * 16 + kb) * 128 + n] = u32x4{l0, l1, l2, l3};
}

// ---------- main ----------
// 8 points/block, M=128 rows: row = c*8 + p (c=0..12 jet channel, p=0..7 point),
// rows 104..127 pad (zeroed once). Abuf packed-word format (round-4 verified):
// word[row*128 + (k ^ ((row&7)<<2))]. Column-split wave tiling: wave wid owns
// output neurons ctb..ctb+31 for ALL rows -> lane's 4 accs hold complete jets
// (4 points x 1 neuron) at static indices; NO D buffer, no D LDS round-trip.
__global__ __launch_bounds__(256, 2)
void pinn_mfma4_kernel(Args args)
{
    __shared__ uint32_t Abuf[128 * 128];     // 64 KB
    __shared__ float    Part[4][2][4][16];   // 2 KB final partial sums

    const int tid   = threadIdx.x;
    const int lane  = tid & 63;
    const int wid   = tid >> 6;
    const int ln31  = lane & 31;
    const int kh    = lane >> 5;
    const int ctb   = wid * 32;
    const int n     = ctb + ln31;            // this lane's output neuron
    const int pbase = blockIdx.x * 8;

    // ---- layer 0: 3 -> 128, jets closed-form; lane does 4 points x 1 neuron ----
    {
        float w0 = args.W0[n * 3], w1 = args.W0[n * 3 + 1], w2 = args.W0[n * 3 + 2];
        float bb = args.b0[n];
        #pragma unroll
        for (int pp = 0; pp < 4; ++pp) {
            const int p = pp + 4 * kh;
            float x = args.xs[pbase + p], y = args.ys[pbase + p], t = args.ts[pbase + p];
            float d[13];
            #pragma unroll
            for (int c = 4; c < 13; ++c) d[c] = 0.f;
            d[0] = w0 * x + w1 * y + w2 * t + bb;
            d[1] = w0; d[2] = w1; d[3] = w2;
            tanh_jet(d);
            #pragma unroll
            for (int c = 0; c < 13; ++c) {
                int row = c * 8 + p;
                Abuf[row * 128 + (n ^ ((row & 7) << 2))] = packA(d[c]);
            }
        }
        // zero pad rows 104..127 once; never written again (tanh writes c<=12 only)
        #pragma unroll
        for (int i = 0; i < 12; ++i)
            Abuf[104 * 128 + tid + 256 * i] = 0;
    }
    __syncthreads();

    for (int L = 1; L <= 7; ++L) {
        const u32x4* whi = args.wpk + (size_t)(L - 1) * 4096;
        const u32x4* wlo = whi + 2048;
        f32x16 acc0{}, acc1{}, acc2{}, acc3{};

        const int sw = (ln31 & 7) << 2;   // (row&7)<<2 with row = 32j+ln31

        #pragma unroll
        for (int ks = 0; ks < 8; ++ks) {
            const int kb = ks * 2 + kh;
            const u32x4 rbh = whi[kb * 128 + n];
            const u32x4 rbl = wlo[kb * 128 + n];
            const bf16x8 bh = __builtin_bit_cast(bf16x8, rbh);
            const bf16x8 bl = __builtin_bit_cast(bf16x8, rbl);

            const int k0 = ks * 16 + kh * 8;
            const int e0 = k0 ^ sw, e1 = (k0 + 4) ^ sw;

            u32x4 w0a = *(const u32x4*)&Abuf[(ln31     ) * 128 + e0];
            u32x4 w0b = *(const u32x4*)&Abuf[(ln31     ) * 128 + e1];
            u32x4 w1a = *(const u32x4*)&Abuf[(ln31 + 32) * 128 + e0];
            u32x4 w1b = *(const u32x4*)&Abuf[(ln31 + 32) * 128 + e1];
            u32x4 w2a = *(const u32x4*)&Abuf[(ln31 + 64) * 128 + e0];
            u32x4 w2b = *(const u32x4*)&Abuf[(ln31 + 64) * 128 + e1];
            u32x4 w3a = *(const u32x4*)&Abuf[(ln31 + 96) * 128 + e0];
            u32x4 w3b = *(const u32x4*)&Abuf[(ln31 + 96) * 128 + e1];

            bf16x8 ah0, al0, ah1, al1, ah2, al2, ah3, al3;
            unpackA(w0a, w0b, ah0, al0);
            unpackA(w1a, w1b, ah1, al1);
            unpackA(w2a, w2b, ah2, al2);
            unpackA(w3a, w3b, ah3, al3);

            acc0 = mfma16(ah0, bh, acc0);
            acc1 = mfma16(ah1, bh, acc1);
            acc2 = mfma16(ah2, bh, acc2);
            acc3 = mfma16(ah3, bh, acc3);
            acc0 = mfma16(al0, bh, acc0);
            acc1 = mfma16(al1, bh, acc1);
            acc2 = mfma16(al2, bh, acc2);
            acc3 = mfma16(al3, bh, acc3);
            acc0 = mfma16(ah0, bl, acc0);
            acc1 = mfma16(ah1, bl, acc1);
            acc2 = mfma16(ah2, bl, acc2);
            acc3 = mfma16(ah3, bl, acc3);
        }

        __syncthreads();   // all waves finished reading A

        // ---- jets straight from accs: acc_j element ((c&3)<<2)|pp holds
        //      row 32j + (i&3) + 8*(i>>2) + 4*kh  =>  c = 4j+(i>>2), p = (i&3)+4kh
        const float bL = args.bias[L][n];
        const float wp = (L == 7) ? args.W8[n]       : 0.f;
        const float wq = (L == 7) ? args.W8[128 + n] : 0.f;

        #pragma unroll
        for (int pp = 0; pp < 4; ++pp) {
            float d[13];
            d[0]  = acc0[pp];      d[1]  = acc0[4 | pp];
            d[2]  = acc0[8 | pp];  d[3]  = acc0[12 | pp];
            d[4]  = acc1[pp];      d[5]  = acc1[4 | pp];
            d[6]  = acc1[8 | pp];  d[7]  = acc1[12 | pp];
            d[8]  = acc2[pp];      d[9]  = acc2[4 | pp];
            d[10] = acc2[8 | pp];  d[11] = acc2[12 | pp];
            d[12] = acc3[pp];
            d[0] += bL;
            tanh_jet(d);

            if (L < 7) {
                #pragma unroll
                for (int c = 0; c < 13; ++c) {
                    int row = c * 8 + pp + 4 * kh;
                    Abuf[row * 128 + (n ^ ((row & 7) << 2))] = packA(d[c]);
                }
            } else {
                float rp[16];
                #pragma unroll
                for (int c = 0; c < 13; ++c) rp[c] = wp * d[c];
                rp[13] = wq * d[0]; rp[14] = wq * d[1]; rp[15] = wq * d[2];
                #pragma unroll
                for (int v = 0; v < 16; ++v) {
                    float s = rp[v];
                    s += __shfl_xor(s, 16); s += __shfl_xor(s, 8);
                    s += __shfl_xor(s, 4);  s += __shfl_xor(s, 2);
                    s += __shfl_xor(s, 1);
                    rp[v] = s;
                }
                if (ln31 == 0) {
                    #pragma unroll
                    for (int v = 0; v < 16; ++v) Part[wid][kh][pp][v] = rp[v];
                }
            }
        }

        if (L < 7) __syncthreads();   // A ready for next layer
    }

    __syncthreads();   // Part visible

    if (tid < 8) {
        const int p = tid, khp = p >> 2, ppp = p & 3;
        float s[16];
        #pragma unroll
        for (int v = 0; v < 16; ++v)
            s[v] = Part[0][khp][ppp][v] + Part[1][khp][ppp][v]
                 + Part[2][khp][ppp][v] + Part[3][khp][ppp][v];

        float l1 = args.l1[0], l2 = args.l2[0];
        float u    = s[2];             // psi_y
        float v    = -s[1];            // -psi_x
        float pv   = s[13] + args.b8[1];
        float u_t  = s[8];             // psi_yt
        float v_t  = -s[7];            // -psi_xt
        float u_x  = s[5];             // psi_xy
        float u_y  = s[6];             // psi_yy
        float v_x  = -s[4];            // -psi_xx
        float v_y  = -s[5];            // -psi_xy
        float u_xx = s[10];            // psi_xxy
        float u_yy = s[12];            // psi_yyy
        float v_xx = -s[9];            // -psi_xxx
        float v_yy = -s[11];           // -psi_xyy
        float p_x = s[14], p_y = s[15];
        float f_u = u_t + l1 * (u * u_x + v * u_y) + p_x - l2 * (u_xx + u_yy);
        float f_v = v_t + l1 * (u * v_x + v * v_y) + p_y - l2 * (v_xx + v_yy);
        const int pt = pbase + p;
        float* out = args.out;
        out[0 * NPTS + pt] = u;
        out[1 * NPTS + pt] = v;
        out[2 * NPTS + pt] = pv;
        out[3 * NPTS + pt] = f_u;
        out[4 * NPTS + pt] = f_v;
    }
}

extern "C" void kernel_launch(void* const* d_in, const int* in_sizes, int n_in,
                              void* d_out, int out_size, void* d_ws, size_t ws_size,
                              hipStream_t stream) {
    PrepArgs pa;
    for (int i = 0; i < 7; ++i) pa.W[i] = (const float*)d_in[2 * (i + 1)];
    pa.dst = (u32x4*)d_ws;   // 7*2*16*128*16B = 448 KB
    pack_w_kernel<<<56, 256, 0, stream>>>(pa);

    Args a;
    a.W0 = (const float*)d_in[0];
    a.b0 = (const float*)d_in[1];
    a.bias[0] = nullptr;
    for (int L = 1; L <= 7; ++L) a.bias[L] = (const float*)d_in[2 * L + 1];
    a.W8 = (const float*)d_in[16];
    a.b8 = (const float*)d_in[17];
    a.xs = (const float*)d_in[18];
    a.ys = (const float*)d_in[19];
    a.ts = (const float*)d_in[20];
    a.l1 = (const float*)d_in[21];
    a.l2 = (const float*)d_in[22];
    a.wpk = (const u32x4*)d_ws;
    a.out = (float*)d_out;

    pinn_mfma4_kernel<<<NPTS / 8, 256, 0, stream>>>(a);
}

// Round 6
// 199.959 us; speedup vs baseline: 3.8906x; 1.0355x over previous
//
#include <hip/hip_runtime.h>
#include <stdint.h>

#define NPTS 16384

typedef __attribute__((ext_vector_type(8)))  __bf16   bf16x8;
typedef __attribute__((ext_vector_type(16))) float    f32x16;
typedef __attribute__((ext_vector_type(4)))  uint32_t u32x4;

struct PrepArgs { const float* W[7]; u32x4* dst; };

struct Args {
    const float* W0; const float* b0;
    const float* bias[8];   // [1..7] valid
    const float* W8; const float* b8;
    const float* xs; const float* ys; const float* ts;
    const float* l1; const float* l2;
    const u32x4* wpk;       // packed W frags in d_ws
    float* out;
};

// ---------- bf16 split helpers (verified) ----------
__device__ __forceinline__ uint32_t b16rne(float x) {
    uint32_t u = __float_as_uint(x);
    return (u + 0x7FFFu + ((u >> 16) & 1u)) >> 16;
}
__device__ __forceinline__ float fromb16(uint32_t h) { return __uint_as_float(h << 16); }

// W pair: hi word (earlier-k in low 16) + lo word (verified prepack format)
__device__ __forceinline__ void packPair(float a, float b, uint32_t& hw, uint32_t& lw) {
    uint32_t ha = b16rne(a), hb = b16rne(b);
    float la = a - fromb16(ha), lb = b - fromb16(hb);
    hw = ha | (hb << 16);
    lw = b16rne(la) | (b16rne(lb) << 16);
}

__device__ __forceinline__ f32x16 mfma16(bf16x8 a, bf16x8 b, f32x16 c) {
    return __builtin_amdgcn_mfma_f32_32x32x16_bf16(a, b, c, 0, 0, 0);
}

__device__ __forceinline__ float fast_tanh(float x) {
    float e = __expf(2.0f * x);
    return 1.0f - __fdividef(2.0f, e + 1.0f);   // inf-safe: e=inf -> 1, e=0 -> -1
}

// ---------- tanh jet ----------
// 0:val 1:dx 2:dy 3:dt 4:dxx 5:dxy 6:dyy 7:dxt 8:dyt 9:dxxx 10:dxxy 11:dxyy 12:dyyy
__device__ __forceinline__ void tanh_jet(float u[13]) {
    float s    = fast_tanh(u[0]);
    float sp   = 1.f - s * s;
    float spp  = -2.f * s * sp;
    float sppp = -2.f * (sp * sp + s * spp);
    float u1 = u[1], u2 = u[2], u3 = u[3];
    float u4 = u[4], u5 = u[5], u6 = u[6];
    u[0] = s;
    u[1] = sp * u1;
    u[2] = sp * u2;
    u[3] = sp * u3;
    u[9]  = sppp * u1 * u1 * u1 + 3.f * spp * u1 * u4 + sp * u[9];
    u[10] = sppp * u1 * u1 * u2 + spp * (u4 * u2 + 2.f * u5 * u1) + sp * u[10];
    u[11] = sppp * u1 * u2 * u2 + spp * (u6 * u1 + 2.f * u5 * u2) + sp * u[11];
    u[12] = sppp * u2 * u2 * u2 + 3.f * spp * u2 * u6 + sp * u[12];
    u[4] = spp * u1 * u1 + sp * u4;
    u[5] = spp * u1 * u2 + sp * u5;
    u[6] = spp * u2 * u2 + sp * u6;
    u[7] = spp * u1 * u3 + sp * u[7];
    u[8] = spp * u2 * u3 + sp * u[8];
}

// ---------- prep: pack W1..W7 into B-frag order (verified, unchanged) ----------
__global__ __launch_bounds__(256)
void pack_w_kernel(PrepArgs a) {
    int idx = blockIdx.x * 256 + threadIdx.x;   // 7*16*128 = 14336
    int L  = idx >> 11;
    int kb = (idx >> 7) & 15;
    int n  = idx & 127;
    const float* w = a.W[L] + n * 128 + kb * 8;
    float4 f0 = *(const float4*)w;
    float4 f1 = *(const float4*)(w + 4);
    uint32_t h0, h1, h2, h3, l0, l1, l2, l3;
    packPair(f0.x, f0.y, h0, l0);
    packPair(f0.z, f0.w, h1, l1);
    packPair(f1.x, f1.y, h2, l2);
    packPair(f1.z, f1.w, h3, l3);
    a.dst[((L * 2 + 0) * 16 + kb) * 128 + n] = u32x4{h0, h1, h2, h3};
    a.dst[((L * 2 + 1) * 16 + kb) * 128 + n] = u32x4{l0, l1, l2, l3};
}

// ---------- main ----------
// 4 points/block, M=64 rows. Row map chosen so MFMA C-layout gives each lane
// complete jets:  row(c,p) = 32*(p&1) + 8*(c>>2) + 4*(p>>1) + (c&3)
//   => lane (ln31,kh), acc_j element i:  c = i (0..12),  p = 2*kh + j.
// A stored as two bf16 planes [64 rows][128 k] with 16B-granule XOR swizzle:
//   elem(row,k) = row*128 + (((k>>3) ^ (row&15))<<3) + (k&7)
// Pad rows (c=13..15): 32s+24+4b+r, r=1..3 — zeroed once, never rewritten.
__global__ __launch_bounds__(256, 4)
void pinn_mfma5_kernel(Args args)
{
    __shared__ ushort Ahi[64 * 128];        // 16 KB
    __shared__ ushort Alo[64 * 128];        // 16 KB
    __shared__ float  Part[4][2][2][16];    // 1 KB

    const int tid   = threadIdx.x;
    const int lane  = tid & 63;
    const int wid   = tid >> 6;
    const int ln31  = lane & 31;
    const int kh    = lane >> 5;
    const int ctb   = wid * 32;
    const int n     = ctb + ln31;           // this lane's neuron (k-index of A, col of W)
    const int pbase = blockIdx.x * 4;

    // ---- layer 0: closed-form jets; lane: neuron n, points p=2kh, 2kh+1 ----
    {
        float w0 = args.W0[n * 3], w1 = args.W0[n * 3 + 1], w2 = args.W0[n * 3 + 2];
        float bb = args.b0[n];
        #pragma unroll
        for (int j = 0; j < 2; ++j) {
            const int p = 2 * kh + j;
            float x = args.xs[pbase + p], y = args.ys[pbase + p], t = args.ts[pbase + p];
            float d[13];
            #pragma unroll
            for (int c = 4; c < 13; ++c) d[c] = 0.f;
            d[0] = w0 * x + w1 * y + w2 * t + bb;
            d[1] = w0; d[2] = w1; d[3] = w2;
            tanh_jet(d);
            #pragma unroll
            for (int c = 0; c < 13; ++c) {
                int row  = 32 * (p & 1) + 8 * (c >> 2) + 4 * (p >> 1) + (c & 3);
                int kidx = (((n >> 3) ^ (row & 15)) << 3) | (n & 7);
                uint32_t h = b16rne(d[c]);
                Ahi[row * 128 + kidx] = (ushort)h;
                Alo[row * 128 + kidx] = (ushort)b16rne(d[c] - fromb16(h));
            }
        }
        // zero the 12 pad rows in both planes (b32 writes; 1536 words total)
        #pragma unroll
        for (int i = 0; i < 6; ++i) {
            int idx  = tid + 256 * i;          // 0..1535
            int pl   = idx >> 9 & 1;           // hmm: 1536 = 2*768; plane = idx/768
            pl = (idx >= 768) ? 1 : 0;
            int rem  = (idx >= 768) ? idx - 768 : idx;
            int rowi = rem >> 6;               // 0..11
            int w    = rem & 63;
            int row  = 24 + 32 * (rowi / 6) + 4 * ((rowi % 6) / 3) + 1 + (rowi % 3);
            uint32_t* P = pl ? (uint32_t*)Alo : (uint32_t*)Ahi;
            P[row * 64 + w] = 0;
        }
    }
    __syncthreads();

    for (int L = 1; L <= 7; ++L) {
        const u32x4* whi = args.wpk + (size_t)(L - 1) * 4096;
        const u32x4* wlo = whi + 2048;
        f32x16 acc0{}, acc1{};

        #pragma unroll
        for (int ks = 0; ks < 8; ++ks) {
            const int kb = ks * 2 + kh;        // k-granule = (ks*16 + kh*8)>>3
            const u32x4 rbh = whi[kb * 128 + n];
            const u32x4 rbl = wlo[kb * 128 + n];

            const int e0 = ln31 * 128        + ((kb ^ (ln31 & 15)) << 3);
            const int e1 = (32 + ln31) * 128 + ((kb ^ (ln31 & 15)) << 3);
            bf16x8 ah0 = __builtin_bit_cast(bf16x8, *(const u32x4*)&Ahi[e0]);
            bf16x8 al0 = __builtin_bit_cast(bf16x8, *(const u32x4*)&Alo[e0]);
            bf16x8 ah1 = __builtin_bit_cast(bf16x8, *(const u32x4*)&Ahi[e1]);
            bf16x8 al1 = __builtin_bit_cast(bf16x8, *(const u32x4*)&Alo[e1]);
            bf16x8 bh  = __builtin_bit_cast(bf16x8, rbh);
            bf16x8 bl  = __builtin_bit_cast(bf16x8, rbl);

            acc0 = mfma16(ah0, bh, acc0);
            acc1 = mfma16(ah1, bh, acc1);
            acc0 = mfma16(al0, bh, acc0);
            acc1 = mfma16(al1, bh, acc1);
            acc0 = mfma16(ah0, bl, acc0);
            acc1 = mfma16(ah1, bl, acc1);
        }

        __syncthreads();   // all waves finished reading A

        const float bL = args.bias[L][n];

        if (L < 7) {
            #pragma unroll
            for (int j = 0; j < 2; ++j) {
                float d[13];
                if (j == 0) {
                    #pragma unroll
                    for (int c = 0; c < 13; ++c) d[c] = acc0[c];
                } else {
                    #pragma unroll
                    for (int c = 0; c < 13; ++c) d[c] = acc1[c];
                }
                d[0] += bL;
                tanh_jet(d);
                const int p = 2 * kh + j;
                #pragma unroll
                for (int c = 0; c < 13; ++c) {
                    int row  = 32 * (p & 1) + 8 * (c >> 2) + 4 * (p >> 1) + (c & 3);
                    int kidx = (((n >> 3) ^ (row & 15)) << 3) | (n & 7);
                    uint32_t h = b16rne(d[c]);
                    Ahi[row * 128 + kidx] = (ushort)h;
                    Alo[row * 128 + kidx] = (ushort)b16rne(d[c] - fromb16(h));
                }
            }
            __syncthreads();   // A ready for next layer
        } else {
            const float wp = args.W8[n], wq = args.W8[128 + n];
            #pragma unroll
            for (int j = 0; j < 2; ++j) {
                float d[13];
                if (j == 0) {
                    #pragma unroll
                    for (int c = 0; c < 13; ++c) d[c] = acc0[c];
                } else {
                    #pragma unroll
                    for (int c = 0; c < 13; ++c) d[c] = acc1[c];
                }
                d[0] += bL;
                tanh_jet(d);
                float rp[16];
                #pragma unroll
                for (int c = 0; c < 13; ++c) rp[c] = wp * d[c];
                rp[13] = wq * d[0]; rp[14] = wq * d[1]; rp[15] = wq * d[2];
                #pragma unroll
                for (int v = 0; v < 16; ++v) {
                    float s = rp[v];
                    s += __shfl_xor(s, 16); s += __shfl_xor(s, 8);
                    s += __shfl_xor(s, 4);  s += __shfl_xor(s, 2);
                    s += __shfl_xor(s, 1);
                    rp[v] = s;
                }
                if (ln31 == 0) {
                    #pragma unroll
                    for (int v = 0; v < 16; ++v) Part[wid][kh][j][v] = rp[v];
                }
            }
        }
    }

    __syncthreads();   // Part visible

    if (tid < 4) {
        const int p = tid, khp = p >> 1, jp = p & 1;
        float s[16];
        #pragma unroll
        for (int v = 0; v < 16; ++v)
            s[v] = Part[0][khp][jp][v] + Part[1][khp][jp][v]
                 + Part[2][khp][jp][v] + Part[3][khp][jp][v];

        float l1 = args.l1[0], l2 = args.l2[0];
        float u    = s[2];             // psi_y
        float v    = -s[1];            // -psi_x
        float pv   = s[13] + args.b8[1];
        float u_t  = s[8];             // psi_yt
        float v_t  = -s[7];            // -psi_xt
        float u_x  = s[5];             // psi_xy
        float u_y  = s[6];             // psi_yy
        float v_x  = -s[4];            // -psi_xx
        float v_y  = -s[5];            // -psi_xy
        float u_xx = s[10];            // psi_xxy
        float u_yy = s[12];            // psi_yyy
        float v_xx = -s[9];            // -psi_xxx
        float v_yy = -s[11];           // -psi_xyy
        float p_x = s[14], p_y = s[15];
        float f_u = u_t + l1 * (u * u_x + v * u_y) + p_x - l2 * (u_xx + u_yy);
        float f_v = v_t + l1 * (u * v_x + v * v_y) + p_y - l2 * (v_xx + v_yy);
        const int pt = pbase + p;
        float* out = args.out;
        out[0 * NPTS + pt] = u;
        out[1 * NPTS + pt] = v;
        out[2 * NPTS + pt] = pv;
        out[3 * NPTS + pt] = f_u;
        out[4 * NPTS + pt] = f_v;
    }
}

extern "C" void kernel_launch(void* const* d_in, const int* in_sizes, int n_in,
                              void* d_out, int out_size, void* d_ws, size_t ws_size,
                              hipStream_t stream) {
    PrepArgs pa;
    for (int i = 0; i < 7; ++i) pa.W[i] = (const float*)d_in[2 * (i + 1)];
    pa.dst = (u32x4*)d_ws;   // 7*2*16*128*16B = 448 KB
    pack_w_kernel<<<56, 256, 0, stream>>>(pa);

    Args a;
    a.W0 = (const float*)d_in[0];
    a.b0 = (const float*)d_in[1];
    a.bias[0] = nullptr;
    for (int L = 1; L <= 7; ++L) a.bias[L] = (const float*)d_in[2 * L + 1];
    a.W8 = (const float*)d_in[16];
    a.b8 = (const float*)d_in[17];
    a.xs = (const float*)d_in[18];
    a.ys = (const float*)d_in[19];
    a.ts = (const float*)d_in[20];
    a.l1 = (const float*)d_in[21];
    a.l2 = (const float*)d_in[22];
    a.wpk = (const u32x4*)d_ws;
    a.out = (float*)d_out;

    pinn_mfma5_kernel<<<NPTS / 4, 256, 0, stream>>>(a);
}

// Round 7
// 187.454 us; speedup vs baseline: 4.1502x; 1.0667x over previous
//
#include <hip/hip_runtime.h>
#include <stdint.h>

#define NPTS 16384

typedef __attribute__((ext_vector_type(8)))  __bf16   bf16x8;
typedef __attribute__((ext_vector_type(16))) float    f32x16;
typedef __attribute__((ext_vector_type(4)))  uint32_t u32x4;

struct PrepArgs { const float* W[7]; u32x4* dst; };

struct Args {
    const float* W0; const float* b0;
    const float* bias[8];   // [1..7] valid
    const float* W8; const float* b8;
    const float* xs; const float* ys; const float* ts;
    const float* l1; const float* l2;
    const u32x4* wpk;       // packed W frags in d_ws
    float* out;
};

// ---------- bf16 helpers ----------
__device__ __forceinline__ uint32_t b16rne(float x) {
    uint32_t u = __float_as_uint(x);
    return (u + 0x7FFFu + ((u >> 16) & 1u)) >> 16;
}
__device__ __forceinline__ float fromb16(uint32_t h) { return __uint_as_float(h << 16); }

// W pair: hi word (earlier-k in low 16) + lo word (verified prepack format)
__device__ __forceinline__ void packPair(float a, float b, uint32_t& hw, uint32_t& lw) {
    uint32_t ha = b16rne(a), hb = b16rne(b);
    float la = a - fromb16(ha), lb = b - fromb16(hb);
    hw = ha | (hb << 16);
    lw = b16rne(la) | (b16rne(lb) << 16);
}

// packed RNE bf16 pair: low16 = bf16(a), high16 = bf16(b)
__device__ __forceinline__ uint32_t cvtpk_bf16(float a, float b) {
    uint32_t r;
    asm("v_cvt_pk_bf16_f32 %0, %1, %2" : "=v"(r) : "v"(a), "v"(b));
    return r;
}

__device__ __forceinline__ f32x16 mfma16(bf16x8 a, bf16x8 b, f32x16 c) {
    return __builtin_amdgcn_mfma_f32_32x32x16_bf16(a, b, c, 0, 0, 0);
}

__device__ __forceinline__ float fast_tanh(float x) {
    float e = __expf(2.0f * x);
    return 1.0f - __fdividef(2.0f, e + 1.0f);   // inf-safe
}

// ---------- tanh jet (verified) ----------
// 0:val 1:dx 2:dy 3:dt 4:dxx 5:dxy 6:dyy 7:dxt 8:dyt 9:dxxx 10:dxxy 11:dxyy 12:dyyy
__device__ __forceinline__ void tanh_jet(float u[13]) {
    float s    = fast_tanh(u[0]);
    float sp   = 1.f - s * s;
    float spp  = -2.f * s * sp;
    float sppp = -2.f * (sp * sp + s * spp);
    float u1 = u[1], u2 = u[2], u3 = u[3];
    float u4 = u[4], u5 = u[5], u6 = u[6];
    u[0] = s;
    u[1] = sp * u1;
    u[2] = sp * u2;
    u[3] = sp * u3;
    u[9]  = sppp * u1 * u1 * u1 + 3.f * spp * u1 * u4 + sp * u[9];
    u[10] = sppp * u1 * u1 * u2 + spp * (u4 * u2 + 2.f * u5 * u1) + sp * u[10];
    u[11] = sppp * u1 * u2 * u2 + spp * (u6 * u1 + 2.f * u5 * u2) + sp * u[11];
    u[12] = sppp * u2 * u2 * u2 + 3.f * spp * u2 * u6 + sp * u[12];
    u[4] = spp * u1 * u1 + sp * u4;
    u[5] = spp * u1 * u2 + sp * u5;
    u[6] = spp * u2 * u2 + sp * u6;
    u[7] = spp * u1 * u3 + sp * u[7];
    u[8] = spp * u2 * u3 + sp * u[8];
}

// ---------- prep: pack W1..W7 into B-frag order (verified, unchanged) ----------
__global__ __launch_bounds__(256)
void pack_w_kernel(PrepArgs a) {
    int idx = blockIdx.x * 256 + threadIdx.x;   // 7*16*128 = 14336
    int L  = idx >> 11;
    int kb = (idx >> 7) & 15;
    int n  = idx & 127;
    const float* w = a.W[L] + n * 128 + kb * 8;
    float4 f0 = *(const float4*)w;
    float4 f1 = *(const float4*)(w + 4);
    uint32_t h0, h1, h2, h3, l0, l1, l2, l3;
    packPair(f0.x, f0.y, h0, l0);
    packPair(f0.z, f0.w, h1, l1);
    packPair(f1.x, f1.y, h2, l2);
    packPair(f1.z, f1.w, h3, l3);
    a.dst[((L * 2 + 0) * 16 + kb) * 128 + n] = u32x4{h0, h1, h2, h3};
    a.dst[((L * 2 + 1) * 16 + kb) * 128 + n] = u32x4{l0, l1, l2, l3};
}

// ---------- main ----------
// 8 points/block, M=128 rows:  row(c,p) = 32*(p&3) + 8*(c>>2) + 4*(p>>2) + (c&3)
//   => lane (ln31,kh), row-tile j, acc_j element i:  c = i (0..12), p = j + 4*kh.
// A: two bf16 planes [128 rows][128 k], 16B-granule XOR swizzle:
//   elem(row,k) = row*128 + (((k>>3) ^ (row&15))<<3) + (k&7)
// Pad rows (c=13..15) zeroed once, never rewritten.
__global__ __launch_bounds__(256, 2)
void pinn_mfma6_kernel(Args args)
{
    __shared__ ushort Ahi[128 * 128];       // 32 KB
    __shared__ ushort Alo[128 * 128];       // 32 KB
    __shared__ float  Part[4][2][4][16];    // 2 KB

    const int tid   = threadIdx.x;
    const int lane  = tid & 63;
    const int wid   = tid >> 6;
    const int ln31  = lane & 31;
    const int kh    = lane >> 5;
    const int n     = wid * 32 + ln31;      // this lane's neuron
    const int pbase = blockIdx.x * 8;

    // packed hi/lo store of one jet (post-tanh) for point-tile j
    auto store_jet = [&](const float d[13], int j) {
        const int rb = 32 * j + 4 * kh;
        #pragma unroll
        for (int cp = 0; cp < 6; ++cp) {
            const int cA = 2 * cp, cB = cA + 1;
            const int rowA = rb + 8 * (cA >> 2) + (cA & 3);
            const int rowB = rb + 8 * (cB >> 2) + (cB & 3);
            const int aA = rowA * 128 + ((((n >> 3) ^ (rowA & 15)) << 3) | (n & 7));
            const int aB = rowB * 128 + ((((n >> 3) ^ (rowB & 15)) << 3) | (n & 7));
            uint32_t hp = cvtpk_bf16(d[cA], d[cB]);
            float hA = __uint_as_float(hp << 16);
            float hB = __uint_as_float(hp & 0xFFFF0000u);
            uint32_t lp = cvtpk_bf16(d[cA] - hA, d[cB] - hB);
            Ahi[aA] = (ushort)hp; Ahi[aB] = (ushort)(hp >> 16);
            Alo[aA] = (ushort)lp; Alo[aB] = (ushort)(lp >> 16);
        }
        {   // c = 12
            const int row = rb + 24;
            const int a12 = row * 128 + ((((n >> 3) ^ (row & 15)) << 3) | (n & 7));
            uint32_t hp = cvtpk_bf16(d[12], 0.f);
            float h = __uint_as_float(hp << 16);
            uint32_t lp = cvtpk_bf16(d[12] - h, 0.f);
            Ahi[a12] = (ushort)hp;
            Alo[a12] = (ushort)lp;
        }
    };

    // ---- layer 0: 3 -> 128 closed-form jets; 4 points (p = j + 4*kh) ----
    {
        float w0 = args.W0[n * 3], w1 = args.W0[n * 3 + 1], w2 = args.W0[n * 3 + 2];
        float bb = args.b0[n];
        #pragma unroll
        for (int j = 0; j < 4; ++j) {
            const int p = j + 4 * kh;
            float x = args.xs[pbase + p], y = args.ys[pbase + p], t = args.ts[pbase + p];
            float d[13];
            #pragma unroll
            for (int c = 4; c < 13; ++c) d[c] = 0.f;
            d[0] = w0 * x + w1 * y + w2 * t + bb;
            d[1] = w0; d[2] = w1; d[3] = w2;
            tanh_jet(d);
            store_jet(d, j);
        }
        // zero 24 pad rows (c=13..15) in both planes: 3072 b32 words
        #pragma unroll
        for (int i = 0; i < 12; ++i) {
            int idx  = tid + 256 * i;               // 0..3071
            int pl   = (idx >= 1536) ? 1 : 0;
            int rem  = idx - 1536 * pl;
            int rowi = rem >> 6;                    // 0..23
            int w    = rem & 63;
            int t4   = rowi / 6, s = rowi - 6 * t4;
            int row  = 32 * t4 + 24 + 4 * (s / 3) + 1 + (s % 3);
            uint32_t* P = pl ? (uint32_t*)Alo : (uint32_t*)Ahi;
            P[row * 64 + w] = 0;
        }
    }
    __syncthreads();

    for (int L = 1; L <= 7; ++L) {
        const u32x4* whi = args.wpk + (size_t)(L - 1) * 4096;
        const u32x4* wlo = whi + 2048;
        f32x16 acc0{}, acc1{}, acc2{}, acc3{};

        #pragma unroll
        for (int ks = 0; ks < 8; ++ks) {
            const int kb = ks * 2 + kh;
            const u32x4 rbh = whi[kb * 128 + n];
            const u32x4 rbl = wlo[kb * 128 + n];

            const int koff = (kb ^ (ln31 & 15)) << 3;
            const int e0 = (ln31      ) * 128 + koff;
            const int e1 = (ln31 + 32 ) * 128 + koff;
            const int e2 = (ln31 + 64 ) * 128 + koff;
            const int e3 = (ln31 + 96 ) * 128 + koff;
            bf16x8 ah0 = __builtin_bit_cast(bf16x8, *(const u32x4*)&Ahi[e0]);
            bf16x8 ah1 = __builtin_bit_cast(bf16x8, *(const u32x4*)&Ahi[e1]);
            bf16x8 ah2 = __builtin_bit_cast(bf16x8, *(const u32x4*)&Ahi[e2]);
            bf16x8 ah3 = __builtin_bit_cast(bf16x8, *(const u32x4*)&Ahi[e3]);
            bf16x8 al0 = __builtin_bit_cast(bf16x8, *(const u32x4*)&Alo[e0]);
            bf16x8 al1 = __builtin_bit_cast(bf16x8, *(const u32x4*)&Alo[e1]);
            bf16x8 al2 = __builtin_bit_cast(bf16x8, *(const u32x4*)&Alo[e2]);
            bf16x8 al3 = __builtin_bit_cast(bf16x8, *(const u32x4*)&Alo[e3]);
            bf16x8 bh  = __builtin_bit_cast(bf16x8, rbh);
            bf16x8 bl  = __builtin_bit_cast(bf16x8, rbl);

            acc0 = mfma16(ah0, bh, acc0);
            acc1 = mfma16(ah1, bh, acc1);
            acc2 = mfma16(ah2, bh, acc2);
            acc3 = mfma16(ah3, bh, acc3);
            acc0 = mfma16(al0, bh, acc0);
            acc1 = mfma16(al1, bh, acc1);
            acc2 = mfma16(al2, bh, acc2);
            acc3 = mfma16(al3, bh, acc3);
            acc0 = mfma16(ah0, bl, acc0);
            acc1 = mfma16(ah1, bl, acc1);
            acc2 = mfma16(ah2, bl, acc2);
            acc3 = mfma16(ah3, bl, acc3);
        }

        __syncthreads();   // all waves finished reading A

        const float bL = args.bias[L][n];

        if (L < 7) {
            #pragma unroll
            for (int j = 0; j < 4; ++j) {
                float d[13];
                #pragma unroll
                for (int c = 0; c < 13; ++c)
                    d[c] = (j == 0) ? acc0[c] : (j == 1) ? acc1[c] : (j == 2) ? acc2[c] : acc3[c];
                d[0] += bL;
                tanh_jet(d);
                store_jet(d, j);
            }
            __syncthreads();   // A ready for next layer
        } else {
            const float wp = args.W8[n], wq = args.W8[128 + n];
            #pragma unroll
            for (int j = 0; j < 4; ++j) {
                float d[13];
                #pragma unroll
                for (int c = 0; c < 13; ++c)
                    d[c] = (j == 0) ? acc0[c] : (j == 1) ? acc1[c] : (j == 2) ? acc2[c] : acc3[c];
                d[0] += bL;
                tanh_jet(d);
                float rp[16];
                #pragma unroll
                for (int c = 0; c < 13; ++c) rp[c] = wp * d[c];
                rp[13] = wq * d[0]; rp[14] = wq * d[1]; rp[15] = wq * d[2];
                #pragma unroll
                for (int v = 0; v < 16; ++v) {
                    float s = rp[v];
                    s += __shfl_xor(s, 16); s += __shfl_xor(s, 8);
                    s += __shfl_xor(s, 4);  s += __shfl_xor(s, 2);
                    s += __shfl_xor(s, 1);
                    rp[v] = s;
                }
                if (ln31 == 0) {
                    #pragma unroll
                    for (int v = 0; v < 16; ++v) Part[wid][kh][j][v] = rp[v];
                }
            }
        }
    }

    __syncthreads();   // Part visible

    if (tid < 8) {
        const int p = tid, khp = p >> 2, jp = p & 3;
        float s[16];
        #pragma unroll
        for (int v = 0; v < 16; ++v)
            s[v] = Part[0][khp][jp][v] + Part[1][khp][jp][v]
                 + Part[2][khp][jp][v] + Part[3][khp][jp][v];

        float l1 = args.l1[0], l2 = args.l2[0];
        float u    = s[2];             // psi_y
        float v    = -s[1];            // -psi_x
        float pv   = s[13] + args.b8[1];
        float u_t  = s[8];             // psi_yt
        float v_t  = -s[7];            // -psi_xt
        float u_x  = s[5];             // psi_xy
        float u_y  = s[6];             // psi_yy
        float v_x  = -s[4];            // -psi_xx
        float v_y  = -s[5];            // -psi_xy
        float u_xx = s[10];            // psi_xxy
        float u_yy = s[12];            // psi_yyy
        float v_xx = -s[9];            // -psi_xxx
        float v_yy = -s[11];           // -psi_xyy
        float p_x = s[14], p_y = s[15];
        float f_u = u_t + l1 * (u * u_x + v * u_y) + p_x - l2 * (u_xx + u_yy);
        float f_v = v_t + l1 * (u * v_x + v * v_y) + p_y - l2 * (v_xx + v_yy);
        const int pt = pbase + p;
        float* out = args.out;
        out[0 * NPTS + pt] = u;
        out[1 * NPTS + pt] = v;
        out[2 * NPTS + pt] = pv;
        out[3 * NPTS + pt] = f_u;
        out[4 * NPTS + pt] = f_v;
    }
}

extern "C" void kernel_launch(void* const* d_in, const int* in_sizes, int n_in,
                              void* d_out, int out_size, void* d_ws, size_t ws_size,
                              hipStream_t stream) {
    PrepArgs pa;
    for (int i = 0; i < 7; ++i) pa.W[i] = (const float*)d_in[2 * (i + 1)];
    pa.dst = (u32x4*)d_ws;   // 7*2*16*128*16B = 448 KB
    pack_w_kernel<<<56, 256, 0, stream>>>(pa);

    Args a;
    a.W0 = (const float*)d_in[0];
    a.b0 = (const float*)d_in[1];
    a.bias[0] = nullptr;
    for (int L = 1; L <= 7; ++L) a.bias[L] = (const float*)d_in[2 * L + 1];
    a.W8 = (const float*)d_in[16];
    a.b8 = (const float*)d_in[17];
    a.xs = (const float*)d_in[18];
    a.ys = (const float*)d_in[19];
    a.ts = (const float*)d_in[20];
    a.l1 = (const float*)d_in[21];
    a.l2 = (const float*)d_in[22];
    a.wpk = (const u32x4*)d_ws;
    a.out = (float*)d_out;

    pinn_mfma6_kernel<<<NPTS / 8, 256, 0, stream>>>(a);
}

// Round 8
// 102.158 us; speedup vs baseline: 7.6154x; 1.8349x over previous
//
#include <hip/hip_runtime.h>
#include <stdint.h>

#define NPTS 16384

typedef __attribute__((ext_vector_type(8)))  __bf16   bf16x8;
typedef __attribute__((ext_vector_type(16))) float    f32x16;
typedef __attribute__((ext_vector_type(4)))  uint32_t u32x4;

struct PrepArgs { const float* W[7]; u32x4* dst; };

struct Args {
    const float* W0; const float* b0;
    const float* bias[8];   // [1..7] valid
    const float* W8; const float* b8;
    const float* xs; const float* ys; const float* ts;
    const float* l1; const float* l2;
    const u32x4* wpk;       // packed W frags in d_ws
    float* out;
};

// ---------- bf16 helpers (verified) ----------
__device__ __forceinline__ uint32_t b16rne(float x) {
    uint32_t u = __float_as_uint(x);
    return (u + 0x7FFFu + ((u >> 16) & 1u)) >> 16;
}
__device__ __forceinline__ float fromb16(uint32_t h) { return __uint_as_float(h << 16); }

__device__ __forceinline__ void packPair(float a, float b, uint32_t& hw, uint32_t& lw) {
    uint32_t ha = b16rne(a), hb = b16rne(b);
    float la = a - fromb16(ha), lb = b - fromb16(hb);
    hw = ha | (hb << 16);
    lw = b16rne(la) | (b16rne(lb) << 16);
}

// packed RNE bf16 pair: low16 = bf16(a), high16 = bf16(b)
__device__ __forceinline__ uint32_t cvtpk_bf16(float a, float b) {
    uint32_t r;
    asm("v_cvt_pk_bf16_f32 %0, %1, %2" : "=v"(r) : "v"(a), "v"(b));
    return r;
}

__device__ __forceinline__ f32x16 mfma16(bf16x8 a, bf16x8 b, f32x16 c) {
    return __builtin_amdgcn_mfma_f32_32x32x16_bf16(a, b, c, 0, 0, 0);
}

__device__ __forceinline__ float fast_tanh(float x) {
    float e = __expf(2.0f * x);
    return 1.0f - __fdividef(2.0f, e + 1.0f);   // inf-safe
}

// ---------- full 13-channel tanh jet (verified) ----------
__device__ __forceinline__ void tanh_jet(float u[13]) {
    float s    = fast_tanh(u[0]);
    float sp   = 1.f - s * s;
    float spp  = -2.f * s * sp;
    float sppp = -2.f * (sp * sp + s * spp);
    float u1 = u[1], u2 = u[2], u3 = u[3];
    float u4 = u[4], u5 = u[5], u6 = u[6];
    u[0] = s;
    u[1] = sp * u1;
    u[2] = sp * u2;
    u[3] = sp * u3;
    u[9]  = sppp * u1 * u1 * u1 + 3.f * spp * u1 * u4 + sp * u[9];
    u[10] = sppp * u1 * u1 * u2 + spp * (u4 * u2 + 2.f * u5 * u1) + sp * u[10];
    u[11] = sppp * u1 * u2 * u2 + spp * (u6 * u1 + 2.f * u5 * u2) + sp * u[11];
    u[12] = sppp * u2 * u2 * u2 + 3.f * spp * u2 * u6 + sp * u[12];
    u[4] = spp * u1 * u1 + sp * u4;
    u[5] = spp * u1 * u2 + sp * u5;
    u[6] = spp * u2 * u2 + sp * u6;
    u[7] = spp * u1 * u3 + sp * u[7];
    u[8] = spp * u2 * u3 + sp * u[8];
}

// ---------- reduced 6-channel jet: 0:val 1:dx 2:dy 3:dt 4:dxt 5:dyt ----------
__device__ __forceinline__ void tanh_jet6(float u[6]) {
    float s   = fast_tanh(u[0]);
    float sp  = 1.f - s * s;
    float spp = -2.f * s * sp;
    float u1 = u[1], u2 = u[2], u3 = u[3];
    u[0] = s;
    u[4] = spp * u1 * u3 + sp * u[4];
    u[5] = spp * u2 * u3 + sp * u[5];
    u[1] = sp * u1;
    u[2] = sp * u2;
    u[3] = sp * u3;
}

// ---------- prep: pack W1..W7 into B-frag order (verified, unchanged) ----------
__global__ __launch_bounds__(256)
void pack_w_kernel(PrepArgs a) {
    int idx = blockIdx.x * 256 + threadIdx.x;   // 7*16*128 = 14336
    int L  = idx >> 11;
    int kb = (idx >> 7) & 15;
    int n  = idx & 127;
    const float* w = a.W[L] + n * 128 + kb * 8;
    float4 f0 = *(const float4*)w;
    float4 f1 = *(const float4*)(w + 4);
    uint32_t h0, h1, h2, h3, l0, l1, l2, l3;
    packPair(f0.x, f0.y, h0, l0);
    packPair(f0.z, f0.w, h1, l1);
    packPair(f1.x, f1.y, h2, l2);
    packPair(f1.z, f1.w, h3, l3);
    a.dst[((L * 2 + 0) * 16 + kb) * 128 + n] = u32x4{h0, h1, h2, h3};
    a.dst[((L * 2 + 1) * 16 + kb) * 128 + n] = u32x4{l0, l1, l2, l3};
}

// ================= reduced path: lambda1 == lambda2 == 0 =================
// 8 points/block, M=64 rows. Slot s = c + 8e (c=0..5 channel, e=point parity);
// row(c,p) = 32t + 4kh + 8*(s>>2) + (s&3), point p = 4t + 2kh + e (t=0..1).
// Lane jets at static acc indices: e=0 -> acc_t[c], e=1 -> acc_t[c+8].
// A: two bf16 planes [64][128], 16B-granule XOR swizzle (verified):
//   addr(row,k) = row*128 + (((k>>3) ^ (row&15))<<3) + (k&7)
// Pad rows {10,11,26,27}+32t+4kh zeroed once.
__global__ __launch_bounds__(256, 4)
void pinn_red_kernel(Args args)
{
    if (args.l1[0] != 0.f || args.l2[0] != 0.f) return;   // uniform guard

    __shared__ ushort Ahi[64 * 128];        // 16 KB
    __shared__ ushort Alo[64 * 128];        // 16 KB
    __shared__ float  Part[4][2][2][2][9];  // 1.2 KB [wid][t][kh][e][v]

    const int tid   = threadIdx.x;
    const int lane  = tid & 63;
    const int wid   = tid >> 6;
    const int ln31  = lane & 31;
    const int kh    = lane >> 5;
    const int n     = wid * 32 + ln31;      // this lane's neuron
    const int pbase = blockIdx.x * 8;

    auto put_pair = [&](float dA, float dB, int rowA) {
        const int rowB = rowA + 1;
        const int aA = rowA * 128 + ((((n >> 3) ^ (rowA & 15)) << 3) | (n & 7));
        const int aB = rowB * 128 + ((((n >> 3) ^ (rowB & 15)) << 3) | (n & 7));
        uint32_t hp = cvtpk_bf16(dA, dB);
        float hA = __uint_as_float(hp << 16);
        float hB = __uint_as_float(hp & 0xFFFF0000u);
        uint32_t lp = cvtpk_bf16(dA - hA, dB - hB);
        Ahi[aA] = (ushort)hp;  Ahi[aB] = (ushort)(hp >> 16);
        Alo[aA] = (ushort)lp;  Alo[aB] = (ushort)(lp >> 16);
    };
    // store jet for (t,e): rows base+{0,1}, base+{2,3}, base+{8,9}, base = 32t+4kh+16e
    auto store_jet6 = [&](const float d[6], int t, int e) {
        const int base = 32 * t + 4 * kh + 16 * e;
        put_pair(d[0], d[1], base);
        put_pair(d[2], d[3], base + 2);
        put_pair(d[4], d[5], base + 8);
    };

    // ---- layer 0: closed-form 6-jets; lane handles 4 (t,e) points ----
    {
        float w0 = args.W0[n * 3], w1 = args.W0[n * 3 + 1], w2 = args.W0[n * 3 + 2];
        float bb = args.b0[n];
        #pragma unroll
        for (int t = 0; t < 2; ++t) {
            #pragma unroll
            for (int e = 0; e < 2; ++e) {
                const int p = 4 * t + 2 * kh + e;
                float x = args.xs[pbase + p], y = args.ys[pbase + p], tt = args.ts[pbase + p];
                float d[6];
                d[0] = w0 * x + w1 * y + w2 * tt + bb;
                d[1] = w0; d[2] = w1; d[3] = w2;
                d[4] = 0.f; d[5] = 0.f;
                tanh_jet6(d);
                store_jet6(d, t, e);
            }
        }
        // zero 16 pad rows (both planes): 2048 b32 words
        #pragma unroll
        for (int i = 0; i < 8; ++i) {
            int idx  = tid + 256 * i;               // 0..2047
            int pl   = (idx >= 1024) ? 1 : 0;
            int rem  = idx - 1024 * pl;
            int rowi = rem >> 6;                    // 0..15
            int w    = rem & 63;
            int row  = 32 * (rowi >> 3) + 4 * ((rowi >> 2) & 1)
                     + ((rowi & 2) ? 26 : 10) + (rowi & 1);
            uint32_t* P = pl ? (uint32_t*)Alo : (uint32_t*)Ahi;
            P[row * 64 + w] = 0;
        }
    }
    __syncthreads();

    for (int L = 1; L <= 7; ++L) {
        const u32x4* whi = args.wpk + (size_t)(L - 1) * 4096;
        const u32x4* wlo = whi + 2048;
        f32x16 acc0{}, acc1{};

        #pragma unroll
        for (int ks = 0; ks < 8; ++ks) {
            const int kb = ks * 2 + kh;
            const u32x4 rbh = whi[kb * 128 + n];
            const u32x4 rbl = wlo[kb * 128 + n];

            const int koff = (kb ^ (ln31 & 15)) << 3;
            const int e0 = (ln31     ) * 128 + koff;
            const int e1 = (ln31 + 32) * 128 + koff;
            bf16x8 ah0 = __builtin_bit_cast(bf16x8, *(const u32x4*)&Ahi[e0]);
            bf16x8 ah1 = __builtin_bit_cast(bf16x8, *(const u32x4*)&Ahi[e1]);
            bf16x8 al0 = __builtin_bit_cast(bf16x8, *(const u32x4*)&Alo[e0]);
            bf16x8 al1 = __builtin_bit_cast(bf16x8, *(const u32x4*)&Alo[e1]);
            bf16x8 bh  = __builtin_bit_cast(bf16x8, rbh);
            bf16x8 bl  = __builtin_bit_cast(bf16x8, rbl);

            acc0 = mfma16(ah0, bh, acc0);
            acc1 = mfma16(ah1, bh, acc1);
            acc0 = mfma16(al0, bh, acc0);
            acc1 = mfma16(al1, bh, acc1);
            acc0 = mfma16(ah0, bl, acc0);
            acc1 = mfma16(ah1, bl, acc1);
        }

        __syncthreads();   // all waves finished reading A

        const float bL = args.bias[L][n];

        if (L < 7) {
            #pragma unroll
            for (int t = 0; t < 2; ++t) {
                #pragma unroll
                for (int e = 0; e < 2; ++e) {
                    float d[6];
                    #pragma unroll
                    for (int c = 0; c < 6; ++c)
                        d[c] = (t == 0) ? acc0[c + 8 * e] : acc1[c + 8 * e];
                    d[0] += bL;
                    tanh_jet6(d);
                    store_jet6(d, t, e);
                }
            }
            __syncthreads();   // A ready for next layer
        } else {
            const float wp = args.W8[n], wq = args.W8[128 + n];
            #pragma unroll
            for (int t = 0; t < 2; ++t) {
                #pragma unroll
                for (int e = 0; e < 2; ++e) {
                    float d[6];
                    #pragma unroll
                    for (int c = 0; c < 6; ++c)
                        d[c] = (t == 0) ? acc0[c + 8 * e] : acc1[c + 8 * e];
                    d[0] += bL;
                    tanh_jet6(d);
                    float rp[9];
                    #pragma unroll
                    for (int c = 0; c < 6; ++c) rp[c] = wp * d[c];
                    rp[6] = wq * d[0]; rp[7] = wq * d[1]; rp[8] = wq * d[2];
                    #pragma unroll
                    for (int v = 0; v < 9; ++v) {
                        float s = rp[v];
                        s += __shfl_xor(s, 16); s += __shfl_xor(s, 8);
                        s += __shfl_xor(s, 4);  s += __shfl_xor(s, 2);
                        s += __shfl_xor(s, 1);
                        rp[v] = s;
                    }
                    if (ln31 == 0) {
                        #pragma unroll
                        for (int v = 0; v < 9; ++v) Part[wid][t][kh][e][v] = rp[v];
                    }
                }
            }
        }
    }

    __syncthreads();   // Part visible

    if (tid < 8) {
        const int p = tid;
        const int t = (p >> 2) & 1, khp = (p >> 1) & 1, e = p & 1;
        float s[9];
        #pragma unroll
        for (int v = 0; v < 9; ++v)
            s[v] = Part[0][t][khp][e][v] + Part[1][t][khp][e][v]
                 + Part[2][t][khp][e][v] + Part[3][t][khp][e][v];

        float u   = s[2];              // psi_y
        float v   = -s[1];             // -psi_x
        float pv  = s[6] + args.b8[1]; // p
        float f_u = s[5] + s[7];       // psi_yt + p_x      (lambda = 0)
        float f_v = -s[4] + s[8];      // -psi_xt + p_y
        const int pt = pbase + p;
        float* out = args.out;
        out[0 * NPTS + pt] = u;
        out[1 * NPTS + pt] = v;
        out[2 * NPTS + pt] = pv;
        out[3 * NPTS + pt] = f_u;
        out[4 * NPTS + pt] = f_v;
    }
}

// ================= full path (R7-verified), runs only when lambda != 0 =========
__global__ __launch_bounds__(256, 2)
void pinn_mfma6_kernel(Args args)
{
    if (args.l1[0] == 0.f && args.l2[0] == 0.f) return;   // reduced path handles it

    __shared__ ushort Ahi[128 * 128];       // 32 KB
    __shared__ ushort Alo[128 * 128];       // 32 KB
    __shared__ float  Part[4][2][4][16];    // 2 KB

    const int tid   = threadIdx.x;
    const int lane  = tid & 63;
    const int wid   = tid >> 6;
    const int ln31  = lane & 31;
    const int kh    = lane >> 5;
    const int n     = wid * 32 + ln31;
    const int pbase = blockIdx.x * 8;

    auto store_jet = [&](const float d[13], int j) {
        const int rb = 32 * j + 4 * kh;
        #pragma unroll
        for (int cp = 0; cp < 6; ++cp) {
            const int cA = 2 * cp, cB = cA + 1;
            const int rowA = rb + 8 * (cA >> 2) + (cA & 3);
            const int rowB = rb + 8 * (cB >> 2) + (cB & 3);
            const int aA = rowA * 128 + ((((n >> 3) ^ (rowA & 15)) << 3) | (n & 7));
            const int aB = rowB * 128 + ((((n >> 3) ^ (rowB & 15)) << 3) | (n & 7));
            uint32_t hp = cvtpk_bf16(d[cA], d[cB]);
            float hA = __uint_as_float(hp << 16);
            float hB = __uint_as_float(hp & 0xFFFF0000u);
            uint32_t lp = cvtpk_bf16(d[cA] - hA, d[cB] - hB);
            Ahi[aA] = (ushort)hp; Ahi[aB] = (ushort)(hp >> 16);
            Alo[aA] = (ushort)lp; Alo[aB] = (ushort)(lp >> 16);
        }
        {
            const int row = rb + 24;
            const int a12 = row * 128 + ((((n >> 3) ^ (row & 15)) << 3) | (n & 7));
            uint32_t hp = cvtpk_bf16(d[12], 0.f);
            float h = __uint_as_float(hp << 16);
            uint32_t lp = cvtpk_bf16(d[12] - h, 0.f);
            Ahi[a12] = (ushort)hp;
            Alo[a12] = (ushort)lp;
        }
    };

    {
        float w0 = args.W0[n * 3], w1 = args.W0[n * 3 + 1], w2 = args.W0[n * 3 + 2];
        float bb = args.b0[n];
        #pragma unroll
        for (int j = 0; j < 4; ++j) {
            const int p = j + 4 * kh;
            float x = args.xs[pbase + p], y = args.ys[pbase + p], t = args.ts[pbase + p];
            float d[13];
            #pragma unroll
            for (int c = 4; c < 13; ++c) d[c] = 0.f;
            d[0] = w0 * x + w1 * y + w2 * t + bb;
            d[1] = w0; d[2] = w1; d[3] = w2;
            tanh_jet(d);
            store_jet(d, j);
        }
        #pragma unroll
        for (int i = 0; i < 12; ++i) {
            int idx  = tid + 256 * i;
            int pl   = (idx >= 1536) ? 1 : 0;
            int rem  = idx - 1536 * pl;
            int rowi = rem >> 6;
            int w    = rem & 63;
            int t4   = rowi / 6, s = rowi - 6 * t4;
            int row  = 32 * t4 + 24 + 4 * (s / 3) + 1 + (s % 3);
            uint32_t* P = pl ? (uint32_t*)Alo : (uint32_t*)Ahi;
            P[row * 64 + w] = 0;
        }
    }
    __syncthreads();

    for (int L = 1; L <= 7; ++L) {
        const u32x4* whi = args.wpk + (size_t)(L - 1) * 4096;
        const u32x4* wlo = whi + 2048;
        f32x16 acc0{}, acc1{}, acc2{}, acc3{};

        #pragma unroll
        for (int ks = 0; ks < 8; ++ks) {
            const int kb = ks * 2 + kh;
            const u32x4 rbh = whi[kb * 128 + n];
            const u32x4 rbl = wlo[kb * 128 + n];

            const int koff = (kb ^ (ln31 & 15)) << 3;
            const int e0 = (ln31      ) * 128 + koff;
            const int e1 = (ln31 + 32 ) * 128 + koff;
            const int e2 = (ln31 + 64 ) * 128 + koff;
            const int e3 = (ln31 + 96 ) * 128 + koff;
            bf16x8 ah0 = __builtin_bit_cast(bf16x8, *(const u32x4*)&Ahi[e0]);
            bf16x8 ah1 = __builtin_bit_cast(bf16x8, *(const u32x4*)&Ahi[e1]);
            bf16x8 ah2 = __builtin_bit_cast(bf16x8, *(const u32x4*)&Ahi[e2]);
            bf16x8 ah3 = __builtin_bit_cast(bf16x8, *(const u32x4*)&Ahi[e3]);
            bf16x8 al0 = __builtin_bit_cast(bf16x8, *(const u32x4*)&Alo[e0]);
            bf16x8 al1 = __builtin_bit_cast(bf16x8, *(const u32x4*)&Alo[e1]);
            bf16x8 al2 = __builtin_bit_cast(bf16x8, *(const u32x4*)&Alo[e2]);
            bf16x8 al3 = __builtin_bit_cast(bf16x8, *(const u32x4*)&Alo[e3]);
            bf16x8 bh  = __builtin_bit_cast(bf16x8, rbh);
            bf16x8 bl  = __builtin_bit_cast(bf16x8, rbl);

            acc0 = mfma16(ah0, bh, acc0);
            acc1 = mfma16(ah1, bh, acc1);
            acc2 = mfma16(ah2, bh, acc2);
            acc3 = mfma16(ah3, bh, acc3);
            acc0 = mfma16(al0, bh, acc0);
            acc1 = mfma16(al1, bh, acc1);
            acc2 = mfma16(al2, bh, acc2);
            acc3 = mfma16(al3, bh, acc3);
            acc0 = mfma16(ah0, bl, acc0);
            acc1 = mfma16(ah1, bl, acc1);
            acc2 = mfma16(ah2, bl, acc2);
            acc3 = mfma16(ah3, bl, acc3);
        }

        __syncthreads();

        const float bL = args.bias[L][n];

        if (L < 7) {
            #pragma unroll
            for (int j = 0; j < 4; ++j) {
                float d[13];
                #pragma unroll
                for (int c = 0; c < 13; ++c)
                    d[c] = (j == 0) ? acc0[c] : (j == 1) ? acc1[c] : (j == 2) ? acc2[c] : acc3[c];
                d[0] += bL;
                tanh_jet(d);
                store_jet(d, j);
            }
            __syncthreads();
        } else {
            const float wp = args.W8[n], wq = args.W8[128 + n];
            #pragma unroll
            for (int j = 0; j < 4; ++j) {
                float d[13];
                #pragma unroll
                for (int c = 0; c < 13; ++c)
                    d[c] = (j == 0) ? acc0[c] : (j == 1) ? acc1[c] : (j == 2) ? acc2[c] : acc3[c];
                d[0] += bL;
                tanh_jet(d);
                float rp[16];
                #pragma unroll
                for (int c = 0; c < 13; ++c) rp[c] = wp * d[c];
                rp[13] = wq * d[0]; rp[14] = wq * d[1]; rp[15] = wq * d[2];
                #pragma unroll
                for (int v = 0; v < 16; ++v) {
                    float s = rp[v];
                    s += __shfl_xor(s, 16); s += __shfl_xor(s, 8);
                    s += __shfl_xor(s, 4);  s += __shfl_xor(s, 2);
                    s += __shfl_xor(s, 1);
                    rp[v] = s;
                }
                if (ln31 == 0) {
                    #pragma unroll
                    for (int v = 0; v < 16; ++v) Part[wid][kh][j][v] = rp[v];
                }
            }
        }
    }

    __syncthreads();

    if (tid < 8) {
        const int p = tid, khp = p >> 2, jp = p & 3;
        float s[16];
        #pragma unroll
        for (int v = 0; v < 16; ++v)
            s[v] = Part[0][khp][jp][v] + Part[1][khp][jp][v]
                 + Part[2][khp][jp][v] + Part[3][khp][jp][v];

        float l1 = args.l1[0], l2 = args.l2[0];
        float u    = s[2];
        float v    = -s[1];
        float pv   = s[13] + args.b8[1];
        float u_t  = s[8];
        float v_t  = -s[7];
        float u_x  = s[5];
        float u_y  = s[6];
        float v_x  = -s[4];
        float v_y  = -s[5];
        float u_xx = s[10];
        float u_yy = s[12];
        float v_xx = -s[9];
        float v_yy = -s[11];
        float p_x = s[14], p_y = s[15];
        float f_u = u_t + l1 * (u * u_x + v * u_y) + p_x - l2 * (u_xx + u_yy);
        float f_v = v_t + l1 * (u * v_x + v * v_y) + p_y - l2 * (v_xx + v_yy);
        const int pt = pbase + p;
        float* out = args.out;
        out[0 * NPTS + pt] = u;
        out[1 * NPTS + pt] = v;
        out[2 * NPTS + pt] = pv;
        out[3 * NPTS + pt] = f_u;
        out[4 * NPTS + pt] = f_v;
    }
}

extern "C" void kernel_launch(void* const* d_in, const int* in_sizes, int n_in,
                              void* d_out, int out_size, void* d_ws, size_t ws_size,
                              hipStream_t stream) {
    PrepArgs pa;
    for (int i = 0; i < 7; ++i) pa.W[i] = (const float*)d_in[2 * (i + 1)];
    pa.dst = (u32x4*)d_ws;   // 448 KB
    pack_w_kernel<<<56, 256, 0, stream>>>(pa);

    Args a;
    a.W0 = (const float*)d_in[0];
    a.b0 = (const float*)d_in[1];
    a.bias[0] = nullptr;
    for (int L = 1; L <= 7; ++L) a.bias[L] = (const float*)d_in[2 * L + 1];
    a.W8 = (const float*)d_in[16];
    a.b8 = (const float*)d_in[17];
    a.xs = (const float*)d_in[18];
    a.ys = (const float*)d_in[19];
    a.ts = (const float*)d_in[20];
    a.l1 = (const float*)d_in[21];
    a.l2 = (const float*)d_in[22];
    a.wpk = (const u32x4*)d_ws;
    a.out = (float*)d_out;

    pinn_red_kernel<<<NPTS / 8, 256, 0, stream>>>(a);     // runs iff lambda == 0
    pinn_mfma6_kernel<<<NPTS / 8, 256, 0, stream>>>(a);   // runs iff lambda != 0
}